// Round 5
// baseline (431.015 us; speedup 1.0000x reference)
//
#include <hip/hip_runtime.h>
#include <hip/hip_bf16.h>
#include <cstdint>

// Problem constants (LongformerSelfAttention: B=2, S=2048, M=768, H=12, D=64, W=256, DIL=1)
#define SEQ    2048
#define HIDDEN 768
#define NHEAD  12
#define HDIM   64
#define WIN    256
#define BATCH  2
#define MTOT   (BATCH * SEQ)   // 4096 tokens

typedef __attribute__((ext_vector_type(8))) short short8;   // 8 bf16 = 4 VGPR (MFMA A/B frag)
typedef __attribute__((ext_vector_type(4))) float f32x4;    // MFMA C/D frag

__device__ __forceinline__ ushort bf16_rne(float f) {
    uint u = __float_as_uint(f);
    uint r = u + 0x7FFFu + ((u >> 16) & 1u);   // round-to-nearest-even
    return (ushort)(r >> 16);
}
__device__ __forceinline__ float bf16_to_f(ushort h) {
    return __uint_as_float(((uint)h) << 16);
}

// ---------------------------------------------------------------------------
// One-pass fp32 -> (hi, lo) bf16 split. Removes the 36x/32x redundant
// per-tile conversion that made proj VALU-bound (45% VALUBusy, 96 us).
// ---------------------------------------------------------------------------
__global__ __launch_bounds__(256) void convert_kernel(
    const float* __restrict__ src, ushort* __restrict__ hi,
    ushort* __restrict__ lo, int n4)
{
    int id = blockIdx.x * 256 + threadIdx.x;
    if (id >= n4) return;
    float4 v = ((const float4*)src)[id];
    ushort h0 = bf16_rne(v.x), h1 = bf16_rne(v.y),
           h2 = bf16_rne(v.z), h3 = bf16_rne(v.w);
    ushort l0 = bf16_rne(v.x - bf16_to_f(h0)),
           l1 = bf16_rne(v.y - bf16_to_f(h1)),
           l2 = bf16_rne(v.z - bf16_to_f(h2)),
           l3 = bf16_rne(v.w - bf16_to_f(h3));
    *(uint2*)&hi[(size_t)id * 4] = make_uint2((uint)h0 | ((uint)h1 << 16),
                                              (uint)h2 | ((uint)h3 << 16));
    *(uint2*)&lo[(size_t)id * 4] = make_uint2((uint)l0 | ((uint)l1 << 16),
                                              (uint)l2 | ((uint)l3 << 16));
}

// ---------------------------------------------------------------------------
// Projection GEMM via split-bf16 MFMA, conversion-free staging.
// Inputs: Xhi/Xlo [4096][768], Whi/Wlo [3][768][768] (bf16 ushorts).
// Outputs (bf16 hi/lo, attention-ready):
//   which 0 -> Q  [bh][s][d]   (scaled by 0.125 after bias)
//   which 1 -> K  [bh][s][d]
//   which 2 -> V^T [bh][d][s]  (transposed for PV staging; packed uint2)
// BM=128, BN=64 (= one head), BK=64, 256 threads = 4 waves 2x2.
// LDS XOR swizzle ^((row&7)<<3) on 8-ushort granularity (16B), conflict-free.
// ---------------------------------------------------------------------------
__global__ __launch_bounds__(256) void proj_mfma_kernel(
    const ushort* __restrict__ Xhi, const ushort* __restrict__ Xlo,
    const ushort* __restrict__ Whi, const ushort* __restrict__ Wlo,
    const float* __restrict__ bq, const float* __restrict__ bk,
    const float* __restrict__ bv,
    ushort* __restrict__ Qhi, ushort* __restrict__ Qlo,
    ushort* __restrict__ Khi_g, ushort* __restrict__ Klo_g,
    ushort* __restrict__ VThi_g, ushort* __restrict__ VTlo_g)
{
    const int which = blockIdx.z;
    const float* __restrict__ bias = (which == 0) ? bq : (which == 1) ? bk : bv;
    const float scale = (which == 0) ? 0.125f : 1.0f;
    const size_t woff = (size_t)which * 768 * 768;

    __shared__ __align__(16) ushort Ahi[128 * 64];
    __shared__ __align__(16) ushort Alo[128 * 64];
    __shared__ __align__(16) ushort Bhi[64 * 64];
    __shared__ __align__(16) ushort Blo[64 * 64];

    const int t  = threadIdx.x;
    const int m0 = blockIdx.x * 128;
    const int h  = blockIdx.y;
    const int n0 = h * 64;

    const int w    = t >> 6;
    const int lane = t & 63;
    const int wr   = w >> 1;
    const int wc   = w & 1;
    const int lr   = lane & 15;
    const int lk   = lane >> 4;

    const int srow = t >> 3;      // staging row (8 threads/row)
    const int sc8  = t & 7;       // 8-ushort chunk within row

    f32x4 acc[4][2];
#pragma unroll
    for (int i = 0; i < 4; ++i)
#pragma unroll
        for (int j = 0; j < 2; ++j) acc[i][j] = (f32x4){0.f, 0.f, 0.f, 0.f};

    for (int k0 = 0; k0 < HIDDEN; k0 += 64) {
        // ---- issue staging loads (bf16, no conversion) ----
        uint4 a_h[4], a_l[4], b_h[2], b_l[2];
#pragma unroll
        for (int i = 0; i < 4; ++i) {       // A: 128 rows x 8 chunks = 1024
            int row = srow + i * 32;
            size_t g = (size_t)(m0 + row) * HIDDEN + k0 + sc8 * 8;
            a_h[i] = *(const uint4*)&Xhi[g];
            a_l[i] = *(const uint4*)&Xlo[g];
        }
#pragma unroll
        for (int i = 0; i < 2; ++i) {       // B: 64 rows x 8 chunks = 512
            int row = srow + i * 32;
            size_t g = woff + (size_t)(n0 + row) * HIDDEN + k0 + sc8 * 8;
            b_h[i] = *(const uint4*)&Whi[g];
            b_l[i] = *(const uint4*)&Wlo[g];
        }
        __syncthreads();   // previous iteration's frag reads done
#pragma unroll
        for (int i = 0; i < 4; ++i) {
            int row = srow + i * 32;
            int idx = (row * 64 + sc8 * 8) ^ ((row & 7) << 3);
            *(uint4*)&Ahi[idx] = a_h[i];
            *(uint4*)&Alo[idx] = a_l[i];
        }
#pragma unroll
        for (int i = 0; i < 2; ++i) {
            int row = srow + i * 32;
            int idx = (row * 64 + sc8 * 8) ^ ((row & 7) << 3);
            *(uint4*)&Bhi[idx] = b_h[i];
            *(uint4*)&Blo[idx] = b_l[i];
        }
        __syncthreads();

#pragma unroll
        for (int s = 0; s < 2; ++s) {
            short8 ah[4], al[4], bh2[2], bl2[2];
#pragma unroll
            for (int fm = 0; fm < 4; ++fm) {
                int row = wr * 64 + fm * 16 + lr;
                int idx = (row * 64 + s * 32 + lk * 8) ^ ((row & 7) << 3);
                ah[fm] = *(const short8*)&Ahi[idx];
                al[fm] = *(const short8*)&Alo[idx];
            }
#pragma unroll
            for (int fn = 0; fn < 2; ++fn) {
                int row = wc * 32 + fn * 16 + lr;
                int idx = (row * 64 + s * 32 + lk * 8) ^ ((row & 7) << 3);
                bh2[fn] = *(const short8*)&Bhi[idx];
                bl2[fn] = *(const short8*)&Blo[idx];
            }
#pragma unroll
            for (int fm = 0; fm < 4; ++fm)
#pragma unroll
                for (int fn = 0; fn < 2; ++fn) {
                    acc[fm][fn] = __builtin_amdgcn_mfma_f32_16x16x32_bf16(
                        ah[fm], bh2[fn], acc[fm][fn], 0, 0, 0);
                    acc[fm][fn] = __builtin_amdgcn_mfma_f32_16x16x32_bf16(
                        ah[fm], bl2[fn], acc[fm][fn], 0, 0, 0);
                    acc[fm][fn] = __builtin_amdgcn_mfma_f32_16x16x32_bf16(
                        al[fm], bh2[fn], acc[fm][fn], 0, 0, 0);
                }
        }
    }

    // ---- epilogue: bias + scale, split to hi/lo, write attention layouts ----
    // C/D layout: col(d) = lr, rows(m) = lk*4 + r  (m89/m91)
    if (which == 2) {
        // V^T [bh][d][s]: 4 consecutive s per (fm,fn) -> packed uint2 stores
#pragma unroll
        for (int fn = 0; fn < 2; ++fn) {
            int d = wc * 32 + fn * 16 + lr;
            float bval = bias[n0 + d];
#pragma unroll
            for (int fm = 0; fm < 4; ++fm) {
                int m  = m0 + wr * 64 + fm * 16 + lk * 4;
                int bb = m >> 11;
                int ss = m & (SEQ - 1);
                ushort hs[4], ls[4];
#pragma unroll
                for (int r = 0; r < 4; ++r) {
                    float val = acc[fm][fn][r] + bval;
                    hs[r] = bf16_rne(val);
                    ls[r] = bf16_rne(val - bf16_to_f(hs[r]));
                }
                size_t base = ((size_t)(bb * NHEAD + h) * HDIM + d) * SEQ + ss;
                *(uint2*)&VThi_g[base] = make_uint2((uint)hs[0] | ((uint)hs[1] << 16),
                                                    (uint)hs[2] | ((uint)hs[3] << 16));
                *(uint2*)&VTlo_g[base] = make_uint2((uint)ls[0] | ((uint)ls[1] << 16),
                                                    (uint)ls[2] | ((uint)ls[3] << 16));
            }
        }
    } else {
        ushort* __restrict__ ohi = (which == 0) ? Qhi : Khi_g;
        ushort* __restrict__ olo = (which == 0) ? Qlo : Klo_g;
#pragma unroll
        for (int fn = 0; fn < 2; ++fn) {
            int d = wc * 32 + fn * 16 + lr;
            float bval = bias[n0 + d];
#pragma unroll
            for (int fm = 0; fm < 4; ++fm) {
#pragma unroll
                for (int r = 0; r < 4; ++r) {
                    int m  = m0 + wr * 64 + fm * 16 + lk * 4 + r;
                    int bb = m >> 11;
                    int ss = m & (SEQ - 1);
                    float val = (acc[fm][fn][r] + bval) * scale;
                    ushort hh = bf16_rne(val);
                    ushort ll = bf16_rne(val - bf16_to_f(hh));
                    size_t base = ((size_t)(bb * NHEAD + h) * SEQ + ss) * HDIM + d;
                    ohi[base] = hh;
                    olo[base] = ll;
                }
            }
        }
    }
}

// ---------------------------------------------------------------------------
// Prefix sum of V over s per (bh,d), from VT hi/lo; vpre is fp32 [bh][d][s].
// 24 blocks x 1024 threads = 64 d-lanes x 16 chunks of 128 (depth 512->128).
// ---------------------------------------------------------------------------
__global__ __launch_bounds__(1024) void vprefix_kernel(
    const ushort* __restrict__ VThi_g, const ushort* __restrict__ VTlo_g,
    float* __restrict__ vpre)
{
    const int bh = blockIdx.x;
    const int d  = threadIdx.x >> 4;    // 0..63
    const int c  = threadIdx.x & 15;    // chunk 0..15
    const size_t base = ((size_t)bh * HDIM + d) * SEQ + c * 128;
    const ushort* ph = &VThi_g[base];
    const ushort* pl = &VTlo_g[base];

    __shared__ float csum[64][16];
    float sum = 0.f;
#pragma unroll 4
    for (int s8 = 0; s8 < 16; ++s8) {
        uint4 H = *(const uint4*)&ph[s8 * 8];
        uint4 L = *(const uint4*)&pl[s8 * 8];
        sum += bf16_to_f((ushort)(H.x & 0xFFFF)) + bf16_to_f((ushort)(L.x & 0xFFFF));
        sum += bf16_to_f((ushort)(H.x >> 16))    + bf16_to_f((ushort)(L.x >> 16));
        sum += bf16_to_f((ushort)(H.y & 0xFFFF)) + bf16_to_f((ushort)(L.y & 0xFFFF));
        sum += bf16_to_f((ushort)(H.y >> 16))    + bf16_to_f((ushort)(L.y >> 16));
        sum += bf16_to_f((ushort)(H.z & 0xFFFF)) + bf16_to_f((ushort)(L.z & 0xFFFF));
        sum += bf16_to_f((ushort)(H.z >> 16))    + bf16_to_f((ushort)(L.z >> 16));
        sum += bf16_to_f((ushort)(H.w & 0xFFFF)) + bf16_to_f((ushort)(L.w & 0xFFFF));
        sum += bf16_to_f((ushort)(H.w >> 16))    + bf16_to_f((ushort)(L.w >> 16));
    }
    csum[d][c] = sum;
    __syncthreads();
    float run = 0.f;
    for (int cc = 0; cc < c; ++cc) run += csum[d][cc];

    float* po = &vpre[base];
    for (int s8 = 0; s8 < 16; ++s8) {
        uint4 H = *(const uint4*)&ph[s8 * 8];
        uint4 L = *(const uint4*)&pl[s8 * 8];
        float f[8];
        f[0] = bf16_to_f((ushort)(H.x & 0xFFFF)) + bf16_to_f((ushort)(L.x & 0xFFFF));
        f[1] = bf16_to_f((ushort)(H.x >> 16))    + bf16_to_f((ushort)(L.x >> 16));
        f[2] = bf16_to_f((ushort)(H.y & 0xFFFF)) + bf16_to_f((ushort)(L.y & 0xFFFF));
        f[3] = bf16_to_f((ushort)(H.y >> 16))    + bf16_to_f((ushort)(L.y >> 16));
        f[4] = bf16_to_f((ushort)(H.z & 0xFFFF)) + bf16_to_f((ushort)(L.z & 0xFFFF));
        f[5] = bf16_to_f((ushort)(H.z >> 16))    + bf16_to_f((ushort)(L.z >> 16));
        f[6] = bf16_to_f((ushort)(H.w & 0xFFFF)) + bf16_to_f((ushort)(L.w & 0xFFFF));
        f[7] = bf16_to_f((ushort)(H.w >> 16))    + bf16_to_f((ushort)(L.w >> 16));
        float buf[8];
#pragma unroll
        for (int j = 0; j < 8; ++j) { run += f[j]; buf[j] = run; }
        *(float4*)&po[s8 * 8]     = make_float4(buf[0], buf[1], buf[2], buf[3]);
        *(float4*)&po[s8 * 8 + 4] = make_float4(buf[4], buf[5], buf[6], buf[7]);
    }
}

// ---------------------------------------------------------------------------
// Banded attention v4 — split-bf16 MFMA, conversion-free staging.
// Inputs are proj-produced hi/lo bf16: Q,K [bh][s][d]; V^T [bh][d][s].
// Core (QK^T swapped, lane-local softmax, PV = V^T . P^T) unchanged from v3.
// ---------------------------------------------------------------------------
__global__ __launch_bounds__(256, 3) void attn_kernel(
    const ushort* __restrict__ Qhi_g, const ushort* __restrict__ Qlo_g,
    const ushort* __restrict__ Khi_g, const ushort* __restrict__ Klo_g,
    const ushort* __restrict__ VThi_g, const ushort* __restrict__ VTlo_g,
    const float* __restrict__ vpre, float* __restrict__ out)
{
    __shared__ __align__(16) ushort Khi[64 * 64], Klo[64 * 64];   // [key][d] ^((key&7)<<3)
    __shared__ __align__(16) ushort VThi[64 * 64], VTlo[64 * 64]; // [d][key] ^((d&7)<<3)
    __shared__ __align__(16) ushort Phi_s[4][16 * 64];            // per-wave [q][key] ^((q&7)<<3)
    __shared__ __align__(16) ushort Plo_s[4][16 * 64];

    const int t    = threadIdx.x;
    const int lane = t & 63;
    const int wv   = t >> 6;                   // wave 0..3 -> q rows wv*16..+15
    const int l15  = lane & 15;
    const int g2   = lane >> 4;                // 0..3

    const int L    = blockIdx.x;
    const int xcd  = L & 7;
    const int slot = L >> 3;                   // 0..95
    const int bh   = xcd * 3 + (slot >> 5);
    const int qb   = slot & 31;
    const int b    = bh / NHEAD;
    const int h    = bh % NHEAD;
    const int i0   = qb * 64;
    const int i    = i0 + wv * 16 + l15;       // this lane's q row (acc column)

    // ---- Q fragments (B-operand), direct bf16 loads ----
    short8 qh[2], qlo[2];
    {
        const size_t qb_ = ((size_t)bh * SEQ + i) * HDIM;
#pragma unroll
        for (int s = 0; s < 2; ++s) {
            qh[s]  = *(const short8*)&Qhi_g[qb_ + s * 32 + g2 * 8];
            qlo[s] = *(const short8*)&Qlo_g[qb_ + s * 32 + g2 * 8];
        }
    }

    // ---- staging: thread covers rows {srow, srow+32} x chunk sc8 of K and VT ----
    const int srow = t >> 3;                   // 0..31
    const int sc8  = t & 7;
    uint4 kh_p[2], kl_p[2], vh_p[2], vl_p[2];

    const int jlo_blk = max(0, i0 - WIN);
    const int jhi_blk = min(SEQ - 1, i0 + 63 + WIN);

    auto LOADT = [&](int jt2) {
        const size_t kb = ((size_t)bh * SEQ + jt2) * HDIM;
#pragma unroll
        for (int u = 0; u < 2; ++u) {
            size_t g = kb + (size_t)(srow + u * 32) * HDIM + sc8 * 8;
            kh_p[u] = *(const uint4*)&Khi_g[g];
            kl_p[u] = *(const uint4*)&Klo_g[g];
        }
        const size_t vb = (size_t)bh * HDIM * SEQ + jt2;
#pragma unroll
        for (int u = 0; u < 2; ++u) {
            size_t g = vb + (size_t)(srow + u * 32) * SEQ + sc8 * 8;
            vh_p[u] = *(const uint4*)&VThi_g[g];
            vl_p[u] = *(const uint4*)&VTlo_g[g];
        }
    };
    auto STORET = [&]() {
#pragma unroll
        for (int u = 0; u < 2; ++u) {
            int row = srow + u * 32;
            int idx = (row * 64 + sc8 * 8) ^ ((row & 7) << 3);
            *(uint4*)&Khi[idx]  = kh_p[u];
            *(uint4*)&Klo[idx]  = kl_p[u];
            *(uint4*)&VThi[idx] = vh_p[u];   // row = d here
            *(uint4*)&VTlo[idx] = vl_p[u];
        }
    };

    float mrun = 0.f, lrun = 0.f;              // mask zeros always in softmax set
    f32x4 ctx[4];
#pragma unroll
    for (int f = 0; f < 4; ++f) ctx[f] = (f32x4){0.f, 0.f, 0.f, 0.f};

    LOADT(jlo_blk);
    STORET();                                   // preload tile 0

    for (int jt = jlo_blk; jt <= jhi_blk; jt += 64) {
        const bool more = (jt + 64) <= jhi_blk;
        if (more) LOADT(jt + 64);               // T14: issue early, write late
        __syncthreads();                        // staged tile visible

        // ---- QK^T: S^T[64 keys][16 q] ----
        f32x4 sacc[4];
#pragma unroll
        for (int f = 0; f < 4; ++f) sacc[f] = (f32x4){0.f, 0.f, 0.f, 0.f};
#pragma unroll
        for (int s = 0; s < 2; ++s) {
            short8 kh[4], kl[4];
#pragma unroll
            for (int f = 0; f < 4; ++f) {
                int row = f * 16 + l15;
                int idx = (row * 64 + s * 32 + g2 * 8) ^ ((row & 7) << 3);
                kh[f] = *(const short8*)&Khi[idx];
                kl[f] = *(const short8*)&Klo[idx];
            }
#pragma unroll
            for (int f = 0; f < 4; ++f) {
                sacc[f] = __builtin_amdgcn_mfma_f32_16x16x32_bf16(kh[f], qh[s],  sacc[f], 0, 0, 0);
                sacc[f] = __builtin_amdgcn_mfma_f32_16x16x32_bf16(kh[f], qlo[s], sacc[f], 0, 0, 0);
                sacc[f] = __builtin_amdgcn_mfma_f32_16x16x32_bf16(kl[f], qh[s],  sacc[f], 0, 0, 0);
            }
        }

        // ---- softmax (lane-local rows; key j = jt + f*16 + g2*4 + r) ----
        float p[4][4];
        float tmax = -1e30f;
#pragma unroll
        for (int f = 0; f < 4; ++f)
#pragma unroll
            for (int r = 0; r < 4; ++r) {
                int j = jt + f * 16 + g2 * 4 + r;
                bool inw = (j >= i - WIN) && (j <= i + WIN);
                float sv_ = inw ? sacc[f][r] : -1e30f;
                p[f][r] = sv_;
                tmax = fmaxf(tmax, sv_);
            }
        tmax = fmaxf(tmax, __shfl_xor(tmax, 16));
        tmax = fmaxf(tmax, __shfl_xor(tmax, 32));
        float m_new = fmaxf(mrun, tmax);
        float resc  = __expf(mrun - m_new);
        float lsum  = 0.f;
#pragma unroll
        for (int f = 0; f < 4; ++f)
#pragma unroll
            for (int r = 0; r < 4; ++r) {
                float pe = __expf(p[f][r] - m_new);
                p[f][r] = pe;
                lsum += pe;
            }
        lsum += __shfl_xor(lsum, 16);
        lsum += __shfl_xor(lsum, 32);
        lrun = lrun * resc + lsum;
        mrun = m_new;
#pragma unroll
        for (int f = 0; f < 4; ++f) {
            ctx[f][0] *= resc; ctx[f][1] *= resc;
            ctx[f][2] *= resc; ctx[f][3] *= resc;
        }

        // ---- P -> bf16 hi/lo into per-wave LDS ([q][key], swizzled) ----
#pragma unroll
        for (int f = 0; f < 4; ++f) {
            ushort h0 = bf16_rne(p[f][0]), h1 = bf16_rne(p[f][1]),
                   h2 = bf16_rne(p[f][2]), h3 = bf16_rne(p[f][3]);
            ushort l0 = bf16_rne(p[f][0] - bf16_to_f(h0)),
                   l1 = bf16_rne(p[f][1] - bf16_to_f(h1)),
                   l2 = bf16_rne(p[f][2] - bf16_to_f(h2)),
                   l3 = bf16_rne(p[f][3] - bf16_to_f(h3));
            int idx = (l15 * 64 + f * 16 + g2 * 4) ^ ((l15 & 7) << 3);
            *(uint2*)&Phi_s[wv][idx] = make_uint2((uint)h0 | ((uint)h1 << 16),
                                                  (uint)h2 | ((uint)h3 << 16));
            *(uint2*)&Plo_s[wv][idx] = make_uint2((uint)l0 | ((uint)l1 << 16),
                                                  (uint)l2 | ((uint)l3 << 16));
        }

        // ---- PV: ctx^T[64 d][16 q] += V^T . P^T ----
#pragma unroll
        for (int s = 0; s < 2; ++s) {
            int pidx = (l15 * 64 + s * 32 + g2 * 8) ^ ((l15 & 7) << 3);
            short8 ph = *(const short8*)&Phi_s[wv][pidx];
            short8 pl = *(const short8*)&Plo_s[wv][pidx];
#pragma unroll
            for (int f = 0; f < 4; ++f) {
                int row = f * 16 + l15;
                int idx = (row * 64 + s * 32 + g2 * 8) ^ ((row & 7) << 3);
                short8 vh = *(const short8*)&VThi[idx];
                short8 vl = *(const short8*)&VTlo[idx];
                ctx[f] = __builtin_amdgcn_mfma_f32_16x16x32_bf16(vh, ph, ctx[f], 0, 0, 0);
                ctx[f] = __builtin_amdgcn_mfma_f32_16x16x32_bf16(vl, ph, ctx[f], 0, 0, 0);
                ctx[f] = __builtin_amdgcn_mfma_f32_16x16x32_bf16(vh, pl, ctx[f], 0, 0, 0);
            }
        }

        __syncthreads();                        // all reads of this tile done
        if (more) STORET();                     // commit prefetched tile
    }

    // ---- out-of-window correction + normalize + store ----
    const int jlo = max(0, i - WIN);
    const int jhi = min(SEQ - 1, i + WIN);
    const int cnt = jhi - jlo + 1;
    const float em   = __expf(-mrun);
    const float ltot = lrun + (float)(SEQ - cnt) * em;
    const float inv  = 1.f / ltot;

    float* orow = &out[((size_t)(b * SEQ + i)) * HIDDEN + h * HDIM];
#pragma unroll
    for (int f = 0; f < 4; ++f) {
        int d0 = f * 16 + g2 * 4;
        float o[4];
#pragma unroll
        for (int j = 0; j < 4; ++j) {
            const float* ch = &vpre[((size_t)bh * HDIM + d0 + j) * SEQ];
            float tt = ch[SEQ - 1];
            float hh = ch[jhi];
            float ll = (jlo > 0) ? ch[jlo - 1] : 0.f;
            o[j] = (ctx[f][j] + em * (tt - hh + ll)) * inv;
        }
        *(float4*)&orow[d0] = make_float4(o[0], o[1], o[2], o[3]);
    }
}

// ---------------------------------------------------------------------------
extern "C" void kernel_launch(void* const* d_in, const int* in_sizes, int n_in,
                              void* d_out, int out_size, void* d_ws, size_t ws_size,
                              hipStream_t stream) {
    const float* X  = (const float*)d_in[0];
    const float* Wq = (const float*)d_in[1];
    const float* bq = (const float*)d_in[2];
    const float* Wk = (const float*)d_in[3];
    const float* bk = (const float*)d_in[4];
    const float* Wv = (const float*)d_in[5];
    const float* bv = (const float*)d_in[6];
    float* out = (float*)d_out;

    const size_t NX = (size_t)MTOT * HIDDEN;          // 3,145,728
    const size_t NW = (size_t)HIDDEN * HIDDEN;        // 589,824
    const size_t NT = (size_t)BATCH * NHEAD * SEQ * HDIM;  // 3,145,728

    ushort* Xhi  = (ushort*)d_ws;              // 6.29 MB  (dead after proj)
    ushort* Xlo  = Xhi  + NX;                  // 6.29 MB  (dead after proj)
    ushort* Whi  = Xlo  + NX;                  // 3.54 MB
    ushort* Wlo  = Whi  + 3 * NW;              // 3.54 MB
    ushort* Qhi  = Wlo  + 3 * NW;              // 6.29 MB
    ushort* Qlo  = Qhi  + NT;
    ushort* Khi  = Qlo  + NT;
    ushort* Klo  = Khi  + NT;
    ushort* VThi = Klo  + NT;
    ushort* VTlo = VThi + NT;                  // total 57.4 MB
    float*  vpre = (float*)d_ws;               // aliases Xhi/Xlo (12.58 MB) after proj

    convert_kernel<<<(int)(NX / 4 / 256), 256, 0, stream>>>(X, Xhi, Xlo, (int)(NX / 4));
    convert_kernel<<<(int)(NW / 4 / 256), 256, 0, stream>>>(Wq, Whi, Wlo, (int)(NW / 4));
    convert_kernel<<<(int)(NW / 4 / 256), 256, 0, stream>>>(Wk, Whi + NW, Wlo + NW, (int)(NW / 4));
    convert_kernel<<<(int)(NW / 4 / 256), 256, 0, stream>>>(Wv, Whi + 2 * NW, Wlo + 2 * NW, (int)(NW / 4));

    proj_mfma_kernel<<<dim3(MTOT / 128, NHEAD, 3), 256, 0, stream>>>(
        Xhi, Xlo, Whi, Wlo, bq, bk, bv, Qhi, Qlo, Khi, Klo, VThi, VTlo);

    vprefix_kernel<<<dim3(BATCH * NHEAD), 1024, 0, stream>>>(VThi, VTlo, vpre);

    attn_kernel<<<dim3((SEQ / 64) * BATCH * NHEAD), 256, 0, stream>>>(
        Qhi, Qlo, Khi, Klo, VThi, VTlo, vpre, out);
}

// Round 6
// 430.485 us; speedup vs baseline: 1.0012x; 1.0012x over previous
//
#include <hip/hip_runtime.h>
#include <hip/hip_bf16.h>
#include <cstdint>

// Problem constants (LongformerSelfAttention: B=2, S=2048, M=768, H=12, D=64, W=256, DIL=1)
#define SEQ    2048
#define HIDDEN 768
#define NHEAD  12
#define HDIM   64
#define WIN    256
#define BATCH  2
#define MTOT   (BATCH * SEQ)   // 4096 tokens

typedef __attribute__((ext_vector_type(8))) short short8;   // 8 bf16 = 4 VGPR (MFMA A/B frag)
typedef __attribute__((ext_vector_type(4))) float f32x4;    // MFMA C/D frag

__device__ __forceinline__ ushort bf16_rne(float f) {
    uint u = __float_as_uint(f);
    uint r = u + 0x7FFFu + ((u >> 16) & 1u);   // round-to-nearest-even
    return (ushort)(r >> 16);
}
__device__ __forceinline__ float bf16_to_f(ushort h) {
    return __uint_as_float(((uint)h) << 16);
}

// ---------------------------------------------------------------------------
// One-pass fp32 -> (hi, lo) bf16 split.
// ---------------------------------------------------------------------------
__global__ __launch_bounds__(256) void convert_kernel(
    const float* __restrict__ src, ushort* __restrict__ hi,
    ushort* __restrict__ lo, int n4)
{
    int id = blockIdx.x * 256 + threadIdx.x;
    if (id >= n4) return;
    float4 v = ((const float4*)src)[id];
    ushort h0 = bf16_rne(v.x), h1 = bf16_rne(v.y),
           h2 = bf16_rne(v.z), h3 = bf16_rne(v.w);
    ushort l0 = bf16_rne(v.x - bf16_to_f(h0)),
           l1 = bf16_rne(v.y - bf16_to_f(h1)),
           l2 = bf16_rne(v.z - bf16_to_f(h2)),
           l3 = bf16_rne(v.w - bf16_to_f(h3));
    *(uint2*)&hi[(size_t)id * 4] = make_uint2((uint)h0 | ((uint)h1 << 16),
                                              (uint)h2 | ((uint)h3 << 16));
    *(uint2*)&lo[(size_t)id * 4] = make_uint2((uint)l0 | ((uint)l1 << 16),
                                              (uint)l2 | ((uint)l3 << 16));
}

// ---------------------------------------------------------------------------
// Projection GEMM via split-bf16 MFMA, conversion-free staging.
// Round 6 fix: epilogue LDS-bounce -> full-cacheline uint4 stores.
// (Round 5's scalar/strided bf16 stores caused 16x HBM write amplification:
//  WRITE_SIZE 588 MB vs 38 MB payload -> 175 us of pure writeback.)
// Outputs: Q,K hi/lo [bh][s][d]; V^T hi/lo [bh][d][s].
// ---------------------------------------------------------------------------
__global__ __launch_bounds__(256) void proj_mfma_kernel(
    const ushort* __restrict__ Xhi, const ushort* __restrict__ Xlo,
    const ushort* __restrict__ Whi, const ushort* __restrict__ Wlo,
    const float* __restrict__ bq, const float* __restrict__ bk,
    const float* __restrict__ bv,
    ushort* __restrict__ Qhi, ushort* __restrict__ Qlo,
    ushort* __restrict__ Khi_g, ushort* __restrict__ Klo_g,
    ushort* __restrict__ VThi_g, ushort* __restrict__ VTlo_g)
{
    const int which = blockIdx.z;
    const float* __restrict__ bias = (which == 0) ? bq : (which == 1) ? bk : bv;
    const float scale = (which == 0) ? 0.125f : 1.0f;
    const size_t woff = (size_t)which * 768 * 768;

    // A buffers sized for epilogue bounce reuse: Q/K needs 128*72, VT 64*136.
    __shared__ __align__(16) ushort Ahi[128 * 72];
    __shared__ __align__(16) ushort Alo[128 * 72];
    __shared__ __align__(16) ushort Bhi[64 * 64];
    __shared__ __align__(16) ushort Blo[64 * 64];

    const int t  = threadIdx.x;
    const int m0 = blockIdx.x * 128;
    const int h  = blockIdx.y;
    const int n0 = h * 64;

    const int w    = t >> 6;
    const int lane = t & 63;
    const int wr   = w >> 1;
    const int wc   = w & 1;
    const int lr   = lane & 15;
    const int lk   = lane >> 4;

    const int srow = t >> 3;      // staging row (8 threads/row)
    const int sc8  = t & 7;       // 8-ushort chunk within row

    f32x4 acc[4][2];
#pragma unroll
    for (int i = 0; i < 4; ++i)
#pragma unroll
        for (int j = 0; j < 2; ++j) acc[i][j] = (f32x4){0.f, 0.f, 0.f, 0.f};

    for (int k0 = 0; k0 < HIDDEN; k0 += 64) {
        // ---- issue staging loads (bf16, no conversion) ----
        uint4 a_h[4], a_l[4], b_h[2], b_l[2];
#pragma unroll
        for (int i = 0; i < 4; ++i) {       // A: 128 rows x 8 chunks
            int row = srow + i * 32;
            size_t g = (size_t)(m0 + row) * HIDDEN + k0 + sc8 * 8;
            a_h[i] = *(const uint4*)&Xhi[g];
            a_l[i] = *(const uint4*)&Xlo[g];
        }
#pragma unroll
        for (int i = 0; i < 2; ++i) {       // B: 64 rows x 8 chunks
            int row = srow + i * 32;
            size_t g = woff + (size_t)(n0 + row) * HIDDEN + k0 + sc8 * 8;
            b_h[i] = *(const uint4*)&Whi[g];
            b_l[i] = *(const uint4*)&Wlo[g];
        }
        __syncthreads();   // previous iteration's frag reads done
#pragma unroll
        for (int i = 0; i < 4; ++i) {
            int row = srow + i * 32;
            int idx = (row * 64 + sc8 * 8) ^ ((row & 7) << 3);
            *(uint4*)&Ahi[idx] = a_h[i];
            *(uint4*)&Alo[idx] = a_l[i];
        }
#pragma unroll
        for (int i = 0; i < 2; ++i) {
            int row = srow + i * 32;
            int idx = (row * 64 + sc8 * 8) ^ ((row & 7) << 3);
            *(uint4*)&Bhi[idx] = b_h[i];
            *(uint4*)&Blo[idx] = b_l[i];
        }
        __syncthreads();

#pragma unroll
        for (int s = 0; s < 2; ++s) {
            short8 ah[4], al[4], bh2[2], bl2[2];
#pragma unroll
            for (int fm = 0; fm < 4; ++fm) {
                int row = wr * 64 + fm * 16 + lr;
                int idx = (row * 64 + s * 32 + lk * 8) ^ ((row & 7) << 3);
                ah[fm] = *(const short8*)&Ahi[idx];
                al[fm] = *(const short8*)&Alo[idx];
            }
#pragma unroll
            for (int fn = 0; fn < 2; ++fn) {
                int row = wc * 32 + fn * 16 + lr;
                int idx = (row * 64 + s * 32 + lk * 8) ^ ((row & 7) << 3);
                bh2[fn] = *(const short8*)&Bhi[idx];
                bl2[fn] = *(const short8*)&Blo[idx];
            }
#pragma unroll
            for (int fm = 0; fm < 4; ++fm)
#pragma unroll
                for (int fn = 0; fn < 2; ++fn) {
                    acc[fm][fn] = __builtin_amdgcn_mfma_f32_16x16x32_bf16(
                        ah[fm], bh2[fn], acc[fm][fn], 0, 0, 0);
                    acc[fm][fn] = __builtin_amdgcn_mfma_f32_16x16x32_bf16(
                        ah[fm], bl2[fn], acc[fm][fn], 0, 0, 0);
                    acc[fm][fn] = __builtin_amdgcn_mfma_f32_16x16x32_bf16(
                        al[fm], bh2[fn], acc[fm][fn], 0, 0, 0);
                }
        }
    }

    // ---- epilogue: bias+scale -> hi/lo, LDS bounce, coalesced uint4 stores ----
    __syncthreads();   // k-loop frag reads complete; Ahi/Alo reusable

    if (which == 2) {
        // stage as [d][136] (padded s-stride); lane owns 4 consecutive s
#pragma unroll
        for (int fn = 0; fn < 2; ++fn) {
            int d = wc * 32 + fn * 16 + lr;
            float bval = bias[n0 + d];
#pragma unroll
            for (int fm = 0; fm < 4; ++fm) {
                int sl = wr * 64 + fm * 16 + lk * 4;
                ushort hs[4], ls[4];
#pragma unroll
                for (int r = 0; r < 4; ++r) {
                    float val = acc[fm][fn][r] + bval;
                    hs[r] = bf16_rne(val);
                    ls[r] = bf16_rne(val - bf16_to_f(hs[r]));
                }
                int idx = d * 136 + sl;
                *(uint2*)&Ahi[idx] = make_uint2((uint)hs[0] | ((uint)hs[1] << 16),
                                                (uint)hs[2] | ((uint)hs[3] << 16));
                *(uint2*)&Alo[idx] = make_uint2((uint)ls[0] | ((uint)ls[1] << 16),
                                                (uint)ls[2] | ((uint)ls[3] << 16));
            }
        }
        __syncthreads();
        // store: thread (d = t>>2, q4 = t&3) -> 64B contiguous per lane-quad
        const int dd = t >> 2, q4 = t & 3;
        const int bb = m0 >> 11, ss = m0 & (SEQ - 1);
        size_t gbase = ((size_t)(bb * NHEAD + h) * HDIM + dd) * SEQ + ss + q4 * 32;
        const int lidx = dd * 136 + q4 * 32;
#pragma unroll
        for (int u = 0; u < 4; ++u) {
            *(uint4*)&VThi_g[gbase + u * 8] = *(const uint4*)&Ahi[lidx + u * 8];
            *(uint4*)&VTlo_g[gbase + u * 8] = *(const uint4*)&Alo[lidx + u * 8];
        }
    } else {
        // stage as [row][72] (padded d-stride)
#pragma unroll
        for (int fn = 0; fn < 2; ++fn) {
            int d = wc * 32 + fn * 16 + lr;
            float bval = bias[n0 + d];
#pragma unroll
            for (int fm = 0; fm < 4; ++fm)
#pragma unroll
                for (int r = 0; r < 4; ++r) {
                    int row = wr * 64 + fm * 16 + lk * 4 + r;
                    float val = (acc[fm][fn][r] + bval) * scale;
                    ushort hh = bf16_rne(val);
                    Ahi[row * 72 + d] = hh;
                    Alo[row * 72 + d] = bf16_rne(val - bf16_to_f(hh));
                }
        }
        __syncthreads();
        // store: thread (row = t>>1, half = t&1) -> 64B per lane, rows contiguous
        ushort* __restrict__ ohi = (which == 0) ? Qhi : Khi_g;
        ushort* __restrict__ olo = (which == 0) ? Qlo : Klo_g;
        const int row = t >> 1, half = t & 1;
        const int m = m0 + row, bb = m >> 11, ss = m & (SEQ - 1);
        size_t gbase = ((size_t)(bb * NHEAD + h) * SEQ + ss) * HDIM + half * 32;
        const int lidx = row * 72 + half * 32;
#pragma unroll
        for (int u = 0; u < 4; ++u) {
            *(uint4*)&ohi[gbase + u * 8] = *(const uint4*)&Ahi[lidx + u * 8];
            *(uint4*)&olo[gbase + u * 8] = *(const uint4*)&Alo[lidx + u * 8];
        }
    }
}

// ---------------------------------------------------------------------------
// Prefix sum of V over s per (bh,d), from VT hi/lo; vpre is fp32 [bh][d][s].
// ---------------------------------------------------------------------------
__global__ __launch_bounds__(1024) void vprefix_kernel(
    const ushort* __restrict__ VThi_g, const ushort* __restrict__ VTlo_g,
    float* __restrict__ vpre)
{
    const int bh = blockIdx.x;
    const int d  = threadIdx.x >> 4;    // 0..63
    const int c  = threadIdx.x & 15;    // chunk 0..15
    const size_t base = ((size_t)bh * HDIM + d) * SEQ + c * 128;
    const ushort* ph = &VThi_g[base];
    const ushort* pl = &VTlo_g[base];

    __shared__ float csum[64][16];
    float sum = 0.f;
#pragma unroll 4
    for (int s8 = 0; s8 < 16; ++s8) {
        uint4 H = *(const uint4*)&ph[s8 * 8];
        uint4 L = *(const uint4*)&pl[s8 * 8];
        sum += bf16_to_f((ushort)(H.x & 0xFFFF)) + bf16_to_f((ushort)(L.x & 0xFFFF));
        sum += bf16_to_f((ushort)(H.x >> 16))    + bf16_to_f((ushort)(L.x >> 16));
        sum += bf16_to_f((ushort)(H.y & 0xFFFF)) + bf16_to_f((ushort)(L.y & 0xFFFF));
        sum += bf16_to_f((ushort)(H.y >> 16))    + bf16_to_f((ushort)(L.y >> 16));
        sum += bf16_to_f((ushort)(H.z & 0xFFFF)) + bf16_to_f((ushort)(L.z & 0xFFFF));
        sum += bf16_to_f((ushort)(H.z >> 16))    + bf16_to_f((ushort)(L.z >> 16));
        sum += bf16_to_f((ushort)(H.w & 0xFFFF)) + bf16_to_f((ushort)(L.w & 0xFFFF));
        sum += bf16_to_f((ushort)(H.w >> 16))    + bf16_to_f((ushort)(L.w >> 16));
    }
    csum[d][c] = sum;
    __syncthreads();
    float run = 0.f;
    for (int cc = 0; cc < c; ++cc) run += csum[d][cc];

    float* po = &vpre[base];
    for (int s8 = 0; s8 < 16; ++s8) {
        uint4 H = *(const uint4*)&ph[s8 * 8];
        uint4 L = *(const uint4*)&pl[s8 * 8];
        float f[8];
        f[0] = bf16_to_f((ushort)(H.x & 0xFFFF)) + bf16_to_f((ushort)(L.x & 0xFFFF));
        f[1] = bf16_to_f((ushort)(H.x >> 16))    + bf16_to_f((ushort)(L.x >> 16));
        f[2] = bf16_to_f((ushort)(H.y & 0xFFFF)) + bf16_to_f((ushort)(L.y & 0xFFFF));
        f[3] = bf16_to_f((ushort)(H.y >> 16))    + bf16_to_f((ushort)(L.y >> 16));
        f[4] = bf16_to_f((ushort)(H.z & 0xFFFF)) + bf16_to_f((ushort)(L.z & 0xFFFF));
        f[5] = bf16_to_f((ushort)(H.z >> 16))    + bf16_to_f((ushort)(L.z >> 16));
        f[6] = bf16_to_f((ushort)(H.w & 0xFFFF)) + bf16_to_f((ushort)(L.w & 0xFFFF));
        f[7] = bf16_to_f((ushort)(H.w >> 16))    + bf16_to_f((ushort)(L.w >> 16));
        float buf[8];
#pragma unroll
        for (int j = 0; j < 8; ++j) { run += f[j]; buf[j] = run; }
        *(float4*)&po[s8 * 8]     = make_float4(buf[0], buf[1], buf[2], buf[3]);
        *(float4*)&po[s8 * 8 + 4] = make_float4(buf[4], buf[5], buf[6], buf[7]);
    }
}

// ---------------------------------------------------------------------------
// Banded attention v4 — split-bf16 MFMA, conversion-free staging (unchanged).
// ---------------------------------------------------------------------------
__global__ __launch_bounds__(256, 3) void attn_kernel(
    const ushort* __restrict__ Qhi_g, const ushort* __restrict__ Qlo_g,
    const ushort* __restrict__ Khi_g, const ushort* __restrict__ Klo_g,
    const ushort* __restrict__ VThi_g, const ushort* __restrict__ VTlo_g,
    const float* __restrict__ vpre, float* __restrict__ out)
{
    __shared__ __align__(16) ushort Khi[64 * 64], Klo[64 * 64];   // [key][d] ^((key&7)<<3)
    __shared__ __align__(16) ushort VThi[64 * 64], VTlo[64 * 64]; // [d][key] ^((d&7)<<3)
    __shared__ __align__(16) ushort Phi_s[4][16 * 64];            // per-wave [q][key] ^((q&7)<<3)
    __shared__ __align__(16) ushort Plo_s[4][16 * 64];

    const int t    = threadIdx.x;
    const int lane = t & 63;
    const int wv   = t >> 6;                   // wave 0..3 -> q rows wv*16..+15
    const int l15  = lane & 15;
    const int g2   = lane >> 4;                // 0..3

    const int L    = blockIdx.x;
    const int xcd  = L & 7;
    const int slot = L >> 3;                   // 0..95
    const int bh   = xcd * 3 + (slot >> 5);
    const int qb   = slot & 31;
    const int b    = bh / NHEAD;
    const int h    = bh % NHEAD;
    const int i0   = qb * 64;
    const int i    = i0 + wv * 16 + l15;       // this lane's q row (acc column)

    // ---- Q fragments (B-operand), direct bf16 loads ----
    short8 qh[2], qlo[2];
    {
        const size_t qb_ = ((size_t)bh * SEQ + i) * HDIM;
#pragma unroll
        for (int s = 0; s < 2; ++s) {
            qh[s]  = *(const short8*)&Qhi_g[qb_ + s * 32 + g2 * 8];
            qlo[s] = *(const short8*)&Qlo_g[qb_ + s * 32 + g2 * 8];
        }
    }

    // ---- staging: thread covers rows {srow, srow+32} x chunk sc8 of K and VT ----
    const int srow = t >> 3;                   // 0..31
    const int sc8  = t & 7;
    uint4 kh_p[2], kl_p[2], vh_p[2], vl_p[2];

    const int jlo_blk = max(0, i0 - WIN);
    const int jhi_blk = min(SEQ - 1, i0 + 63 + WIN);

    auto LOADT = [&](int jt2) {
        const size_t kb = ((size_t)bh * SEQ + jt2) * HDIM;
#pragma unroll
        for (int u = 0; u < 2; ++u) {
            size_t g = kb + (size_t)(srow + u * 32) * HDIM + sc8 * 8;
            kh_p[u] = *(const uint4*)&Khi_g[g];
            kl_p[u] = *(const uint4*)&Klo_g[g];
        }
        const size_t vb = (size_t)bh * HDIM * SEQ + jt2;
#pragma unroll
        for (int u = 0; u < 2; ++u) {
            size_t g = vb + (size_t)(srow + u * 32) * SEQ + sc8 * 8;
            vh_p[u] = *(const uint4*)&VThi_g[g];
            vl_p[u] = *(const uint4*)&VTlo_g[g];
        }
    };
    auto STORET = [&]() {
#pragma unroll
        for (int u = 0; u < 2; ++u) {
            int row = srow + u * 32;
            int idx = (row * 64 + sc8 * 8) ^ ((row & 7) << 3);
            *(uint4*)&Khi[idx]  = kh_p[u];
            *(uint4*)&Klo[idx]  = kl_p[u];
            *(uint4*)&VThi[idx] = vh_p[u];   // row = d here
            *(uint4*)&VTlo[idx] = vl_p[u];
        }
    };

    float mrun = 0.f, lrun = 0.f;              // mask zeros always in softmax set
    f32x4 ctx[4];
#pragma unroll
    for (int f = 0; f < 4; ++f) ctx[f] = (f32x4){0.f, 0.f, 0.f, 0.f};

    LOADT(jlo_blk);
    STORET();                                   // preload tile 0

    for (int jt = jlo_blk; jt <= jhi_blk; jt += 64) {
        const bool more = (jt + 64) <= jhi_blk;
        if (more) LOADT(jt + 64);               // T14: issue early, write late
        __syncthreads();                        // staged tile visible

        // ---- QK^T: S^T[64 keys][16 q] ----
        f32x4 sacc[4];
#pragma unroll
        for (int f = 0; f < 4; ++f) sacc[f] = (f32x4){0.f, 0.f, 0.f, 0.f};
#pragma unroll
        for (int s = 0; s < 2; ++s) {
            short8 kh[4], kl[4];
#pragma unroll
            for (int f = 0; f < 4; ++f) {
                int row = f * 16 + l15;
                int idx = (row * 64 + s * 32 + g2 * 8) ^ ((row & 7) << 3);
                kh[f] = *(const short8*)&Khi[idx];
                kl[f] = *(const short8*)&Klo[idx];
            }
#pragma unroll
            for (int f = 0; f < 4; ++f) {
                sacc[f] = __builtin_amdgcn_mfma_f32_16x16x32_bf16(kh[f], qh[s],  sacc[f], 0, 0, 0);
                sacc[f] = __builtin_amdgcn_mfma_f32_16x16x32_bf16(kh[f], qlo[s], sacc[f], 0, 0, 0);
                sacc[f] = __builtin_amdgcn_mfma_f32_16x16x32_bf16(kl[f], qh[s],  sacc[f], 0, 0, 0);
            }
        }

        // ---- softmax (lane-local rows; key j = jt + f*16 + g2*4 + r) ----
        float p[4][4];
        float tmax = -1e30f;
#pragma unroll
        for (int f = 0; f < 4; ++f)
#pragma unroll
            for (int r = 0; r < 4; ++r) {
                int j = jt + f * 16 + g2 * 4 + r;
                bool inw = (j >= i - WIN) && (j <= i + WIN);
                float sv_ = inw ? sacc[f][r] : -1e30f;
                p[f][r] = sv_;
                tmax = fmaxf(tmax, sv_);
            }
        tmax = fmaxf(tmax, __shfl_xor(tmax, 16));
        tmax = fmaxf(tmax, __shfl_xor(tmax, 32));
        float m_new = fmaxf(mrun, tmax);
        float resc  = __expf(mrun - m_new);
        float lsum  = 0.f;
#pragma unroll
        for (int f = 0; f < 4; ++f)
#pragma unroll
            for (int r = 0; r < 4; ++r) {
                float pe = __expf(p[f][r] - m_new);
                p[f][r] = pe;
                lsum += pe;
            }
        lsum += __shfl_xor(lsum, 16);
        lsum += __shfl_xor(lsum, 32);
        lrun = lrun * resc + lsum;
        mrun = m_new;
#pragma unroll
        for (int f = 0; f < 4; ++f) {
            ctx[f][0] *= resc; ctx[f][1] *= resc;
            ctx[f][2] *= resc; ctx[f][3] *= resc;
        }

        // ---- P -> bf16 hi/lo into per-wave LDS ([q][key], swizzled) ----
#pragma unroll
        for (int f = 0; f < 4; ++f) {
            ushort h0 = bf16_rne(p[f][0]), h1 = bf16_rne(p[f][1]),
                   h2 = bf16_rne(p[f][2]), h3 = bf16_rne(p[f][3]);
            ushort l0 = bf16_rne(p[f][0] - bf16_to_f(h0)),
                   l1 = bf16_rne(p[f][1] - bf16_to_f(h1)),
                   l2 = bf16_rne(p[f][2] - bf16_to_f(h2)),
                   l3 = bf16_rne(p[f][3] - bf16_to_f(h3));
            int idx = (l15 * 64 + f * 16 + g2 * 4) ^ ((l15 & 7) << 3);
            *(uint2*)&Phi_s[wv][idx] = make_uint2((uint)h0 | ((uint)h1 << 16),
                                                  (uint)h2 | ((uint)h3 << 16));
            *(uint2*)&Plo_s[wv][idx] = make_uint2((uint)l0 | ((uint)l1 << 16),
                                                  (uint)l2 | ((uint)l3 << 16));
        }

        // ---- PV: ctx^T[64 d][16 q] += V^T . P^T ----
#pragma unroll
        for (int s = 0; s < 2; ++s) {
            int pidx = (l15 * 64 + s * 32 + g2 * 8) ^ ((l15 & 7) << 3);
            short8 ph = *(const short8*)&Phi_s[wv][pidx];
            short8 pl = *(const short8*)&Plo_s[wv][pidx];
#pragma unroll
            for (int f = 0; f < 4; ++f) {
                int row = f * 16 + l15;
                int idx = (row * 64 + s * 32 + g2 * 8) ^ ((row & 7) << 3);
                short8 vh = *(const short8*)&VThi[idx];
                short8 vl = *(const short8*)&VTlo[idx];
                ctx[f] = __builtin_amdgcn_mfma_f32_16x16x32_bf16(vh, ph, ctx[f], 0, 0, 0);
                ctx[f] = __builtin_amdgcn_mfma_f32_16x16x32_bf16(vl, ph, ctx[f], 0, 0, 0);
                ctx[f] = __builtin_amdgcn_mfma_f32_16x16x32_bf16(vh, pl, ctx[f], 0, 0, 0);
            }
        }

        __syncthreads();                        // all reads of this tile done
        if (more) STORET();                     // commit prefetched tile
    }

    // ---- out-of-window correction + normalize + store ----
    const int jlo = max(0, i - WIN);
    const int jhi = min(SEQ - 1, i + WIN);
    const int cnt = jhi - jlo + 1;
    const float em   = __expf(-mrun);
    const float ltot = lrun + (float)(SEQ - cnt) * em;
    const float inv  = 1.f / ltot;

    float* orow = &out[((size_t)(b * SEQ + i)) * HIDDEN + h * HDIM];
#pragma unroll
    for (int f = 0; f < 4; ++f) {
        int d0 = f * 16 + g2 * 4;
        float o[4];
#pragma unroll
        for (int j = 0; j < 4; ++j) {
            const float* ch = &vpre[((size_t)bh * HDIM + d0 + j) * SEQ];
            float tt = ch[SEQ - 1];
            float hh = ch[jhi];
            float ll = (jlo > 0) ? ch[jlo - 1] : 0.f;
            o[j] = (ctx[f][j] + em * (tt - hh + ll)) * inv;
        }
        *(float4*)&orow[d0] = make_float4(o[0], o[1], o[2], o[3]);
    }
}

// ---------------------------------------------------------------------------
extern "C" void kernel_launch(void* const* d_in, const int* in_sizes, int n_in,
                              void* d_out, int out_size, void* d_ws, size_t ws_size,
                              hipStream_t stream) {
    const float* X  = (const float*)d_in[0];
    const float* Wq = (const float*)d_in[1];
    const float* bq = (const float*)d_in[2];
    const float* Wk = (const float*)d_in[3];
    const float* bk = (const float*)d_in[4];
    const float* Wv = (const float*)d_in[5];
    const float* bv = (const float*)d_in[6];
    float* out = (float*)d_out;

    const size_t NX = (size_t)MTOT * HIDDEN;          // 3,145,728
    const size_t NW = (size_t)HIDDEN * HIDDEN;        // 589,824
    const size_t NT = (size_t)BATCH * NHEAD * SEQ * HDIM;  // 3,145,728

    ushort* Xhi  = (ushort*)d_ws;              // dead after proj
    ushort* Xlo  = Xhi  + NX;                  // dead after proj
    ushort* Whi  = Xlo  + NX;
    ushort* Wlo  = Whi  + 3 * NW;
    ushort* Qhi  = Wlo  + 3 * NW;
    ushort* Qlo  = Qhi  + NT;
    ushort* Khi  = Qlo  + NT;
    ushort* Klo  = Khi  + NT;
    ushort* VThi = Klo  + NT;
    ushort* VTlo = VThi + NT;                  // total 57.4 MB
    float*  vpre = (float*)d_ws;               // aliases Xhi/Xlo after proj

    convert_kernel<<<(int)(NX / 4 / 256), 256, 0, stream>>>(X, Xhi, Xlo, (int)(NX / 4));
    convert_kernel<<<(int)(NW / 4 / 256), 256, 0, stream>>>(Wq, Whi, Wlo, (int)(NW / 4));
    convert_kernel<<<(int)(NW / 4 / 256), 256, 0, stream>>>(Wk, Whi + NW, Wlo + NW, (int)(NW / 4));
    convert_kernel<<<(int)(NW / 4 / 256), 256, 0, stream>>>(Wv, Whi + 2 * NW, Wlo + 2 * NW, (int)(NW / 4));

    proj_mfma_kernel<<<dim3(MTOT / 128, NHEAD, 3), 256, 0, stream>>>(
        Xhi, Xlo, Whi, Wlo, bq, bk, bv, Qhi, Qlo, Khi, Klo, VThi, VTlo);

    vprefix_kernel<<<dim3(BATCH * NHEAD), 1024, 0, stream>>>(VThi, VTlo, vpre);

    attn_kernel<<<dim3((SEQ / 64) * BATCH * NHEAD), 256, 0, stream>>>(
        Qhi, Qlo, Khi, Klo, VThi, VTlo, vpre, out);
}

// Round 8
// 392.757 us; speedup vs baseline: 1.0974x; 1.0961x over previous
//
#include <hip/hip_runtime.h>
#include <hip/hip_bf16.h>
#include <cstdint>

// Problem constants (LongformerSelfAttention: B=2, S=2048, M=768, H=12, D=64, W=256, DIL=1)
#define SEQ    2048
#define HIDDEN 768
#define NHEAD  12
#define HDIM   64
#define WIN    256
#define BATCH  2
#define MTOT   (BATCH * SEQ)   // 4096 tokens

typedef __attribute__((ext_vector_type(8))) short short8;   // 8 bf16 = 4 VGPR (MFMA A/B frag)
typedef __attribute__((ext_vector_type(4))) float f32x4;    // MFMA C/D frag

__device__ __forceinline__ ushort bf16_rne(float f) {
    uint u = __float_as_uint(f);
    uint r = u + 0x7FFFu + ((u >> 16) & 1u);   // round-to-nearest-even
    return (ushort)(r >> 16);
}
__device__ __forceinline__ float bf16_to_f(ushort h) {
    return __uint_as_float(((uint)h) << 16);
}

// ---------------------------------------------------------------------------
// One-pass fp32 -> (hi, lo) bf16 split for X and W (read-side only).
// NOTE (R5/R6 lesson): bf16 hi/lo as *GEMM outputs* caused 15.7x HBM write
// amplification (580 MB vs 38 MB payload) regardless of store pattern;
// fp32 outputs in the 64B-segment epilogue measured clean (R4: 36.8 MB).
// So hi/lo materialization is used ONLY for the k-dim staging inputs.
// ---------------------------------------------------------------------------
__global__ __launch_bounds__(256) void convert_kernel(
    const float* __restrict__ src, ushort* __restrict__ hi,
    ushort* __restrict__ lo, int n4)
{
    int id = blockIdx.x * 256 + threadIdx.x;
    if (id >= n4) return;
    float4 v = ((const float4*)src)[id];
    ushort h0 = bf16_rne(v.x), h1 = bf16_rne(v.y),
           h2 = bf16_rne(v.z), h3 = bf16_rne(v.w);
    ushort l0 = bf16_rne(v.x - bf16_to_f(h0)),
           l1 = bf16_rne(v.y - bf16_to_f(h1)),
           l2 = bf16_rne(v.z - bf16_to_f(h2)),
           l3 = bf16_rne(v.w - bf16_to_f(h3));
    *(uint2*)&hi[(size_t)id * 4] = make_uint2((uint)h0 | ((uint)h1 << 16),
                                              (uint)h2 | ((uint)h3 << 16));
    *(uint2*)&lo[(size_t)id * 4] = make_uint2((uint)l0 | ((uint)l1 << 16),
                                              (uint)l2 | ((uint)l3 << 16));
}

// ---------------------------------------------------------------------------
// Projection GEMM via split-bf16 MFMA.
// Read side (R6, proven): pre-converted Xhi/Xlo/Whi/Wlo staged with pure
// uint4 loads + swizzled ds_write (VALUBusy 4.6%).
// Write side (R4, proven): fp32 Q/K/V [bh][s][d], 64B-segment stores
// (WRITE_SIZE 36.8 MB, no amplification).
// BM=128, BN=64 (= one head), BK=64, 256 threads = 4 waves 2x2.
// ---------------------------------------------------------------------------
__global__ __launch_bounds__(256) void proj_mfma_kernel(
    const ushort* __restrict__ Xhi, const ushort* __restrict__ Xlo,
    const ushort* __restrict__ Whi, const ushort* __restrict__ Wlo,
    const float* __restrict__ bq, const float* __restrict__ bk,
    const float* __restrict__ bv,
    float* __restrict__ Qo, float* __restrict__ Ko, float* __restrict__ Vo)
{
    const int which = blockIdx.z;
    const float* __restrict__ bias = (which == 0) ? bq : (which == 1) ? bk : bv;
    float* __restrict__ out        = (which == 0) ? Qo : (which == 1) ? Ko : Vo;
    const float scale = (which == 0) ? 0.125f : 1.0f;
    const size_t woff = (size_t)which * 768 * 768;

    __shared__ __align__(16) ushort Ahi[128 * 64];
    __shared__ __align__(16) ushort Alo[128 * 64];
    __shared__ __align__(16) ushort Bhi[64 * 64];
    __shared__ __align__(16) ushort Blo[64 * 64];

    const int t  = threadIdx.x;
    const int m0 = blockIdx.x * 128;
    const int h  = blockIdx.y;
    const int n0 = h * 64;

    const int w    = t >> 6;
    const int lane = t & 63;
    const int wr   = w >> 1;
    const int wc   = w & 1;
    const int lr   = lane & 15;
    const int lk   = lane >> 4;

    const int srow = t >> 3;      // staging row (8 threads/row)
    const int sc8  = t & 7;       // 8-ushort chunk within row

    f32x4 acc[4][2];
#pragma unroll
    for (int i = 0; i < 4; ++i)
#pragma unroll
        for (int j = 0; j < 2; ++j) acc[i][j] = (f32x4){0.f, 0.f, 0.f, 0.f};

    for (int k0 = 0; k0 < HIDDEN; k0 += 64) {
        // ---- issue staging loads (bf16, no conversion) ----
        uint4 a_h[4], a_l[4], b_h[2], b_l[2];
#pragma unroll
        for (int i = 0; i < 4; ++i) {       // A: 128 rows x 8 chunks
            int row = srow + i * 32;
            size_t g = (size_t)(m0 + row) * HIDDEN + k0 + sc8 * 8;
            a_h[i] = *(const uint4*)&Xhi[g];
            a_l[i] = *(const uint4*)&Xlo[g];
        }
#pragma unroll
        for (int i = 0; i < 2; ++i) {       // B: 64 rows x 8 chunks
            int row = srow + i * 32;
            size_t g = woff + (size_t)(n0 + row) * HIDDEN + k0 + sc8 * 8;
            b_h[i] = *(const uint4*)&Whi[g];
            b_l[i] = *(const uint4*)&Wlo[g];
        }
        __syncthreads();   // previous iteration's frag reads done
#pragma unroll
        for (int i = 0; i < 4; ++i) {
            int row = srow + i * 32;
            int idx = (row * 64 + sc8 * 8) ^ ((row & 7) << 3);
            *(uint4*)&Ahi[idx] = a_h[i];
            *(uint4*)&Alo[idx] = a_l[i];
        }
#pragma unroll
        for (int i = 0; i < 2; ++i) {
            int row = srow + i * 32;
            int idx = (row * 64 + sc8 * 8) ^ ((row & 7) << 3);
            *(uint4*)&Bhi[idx] = b_h[i];
            *(uint4*)&Blo[idx] = b_l[i];
        }
        __syncthreads();

#pragma unroll
        for (int s = 0; s < 2; ++s) {
            short8 ah[4], al[4], bh2[2], bl2[2];
#pragma unroll
            for (int fm = 0; fm < 4; ++fm) {
                int row = wr * 64 + fm * 16 + lr;
                int idx = (row * 64 + s * 32 + lk * 8) ^ ((row & 7) << 3);
                ah[fm] = *(const short8*)&Ahi[idx];
                al[fm] = *(const short8*)&Alo[idx];
            }
#pragma unroll
            for (int fn = 0; fn < 2; ++fn) {
                int row = wc * 32 + fn * 16 + lr;
                int idx = (row * 64 + s * 32 + lk * 8) ^ ((row & 7) << 3);
                bh2[fn] = *(const short8*)&Bhi[idx];
                bl2[fn] = *(const short8*)&Blo[idx];
            }
#pragma unroll
            for (int fm = 0; fm < 4; ++fm)
#pragma unroll
                for (int fn = 0; fn < 2; ++fn) {
                    acc[fm][fn] = __builtin_amdgcn_mfma_f32_16x16x32_bf16(
                        ah[fm], bh2[fn], acc[fm][fn], 0, 0, 0);
                    acc[fm][fn] = __builtin_amdgcn_mfma_f32_16x16x32_bf16(
                        ah[fm], bl2[fn], acc[fm][fn], 0, 0, 0);
                    acc[fm][fn] = __builtin_amdgcn_mfma_f32_16x16x32_bf16(
                        al[fm], bh2[fn], acc[fm][fn], 0, 0, 0);
                }
        }
    }

    // ---- epilogue (R4-proven): fp32 stores, 64B contiguous per 16-lane group ----
#pragma unroll
    for (int fn = 0; fn < 2; ++fn) {
        int d = wc * 32 + fn * 16 + lr;
        float bval = bias[n0 + d];
#pragma unroll
        for (int fm = 0; fm < 4; ++fm) {
#pragma unroll
            for (int r = 0; r < 4; ++r) {
                int m  = m0 + wr * 64 + fm * 16 + lk * 4 + r;
                int bb = m >> 11;
                int ss = m & (SEQ - 1);
                out[(((size_t)(bb * NHEAD + h) * SEQ) + ss) * HDIM + d] =
                    (acc[fm][fn][r] + bval) * scale;
            }
        }
    }
}

// ---------------------------------------------------------------------------
// Prefix sum of V along sequence per (b,h,d) (R4 verbatim; V fp32 [bh][s][d]).
// ---------------------------------------------------------------------------
__global__ __launch_bounds__(256) void vprefix_kernel(
    const float* __restrict__ V, float* __restrict__ Vpre)
{
    const int bh    = blockIdx.x;
    const int d     = threadIdx.x & 63;
    const int chunk = threadIdx.x >> 6;
    const float* vb = &V[(size_t)bh * SEQ * HDIM];
    float* pb       = &Vpre[(size_t)bh * SEQ * HDIM];

    __shared__ float csum[4][64];
    const int s0 = chunk * 512;
    float sum = 0.f;
    for (int s = s0; s < s0 + 512; ++s) sum += vb[(size_t)s * HDIM + d];
    csum[chunk][d] = sum;
    __syncthreads();
    float run = 0.f;
    for (int c = 0; c < chunk; ++c) run += csum[c][d];
    for (int s = s0; s < s0 + 512; ++s) {
        run += vb[(size_t)s * HDIM + d];
        pb[(size_t)s * HDIM + d] = run;
    }
}

// ---------------------------------------------------------------------------
// Banded attention (R4 verbatim — split-bf16 MFMA, both GEMMs operand-swapped,
// fp32 Q/K/V inputs with in-staging hi/lo conversion; proven ~90 us).
// ---------------------------------------------------------------------------
__global__ __launch_bounds__(256, 3) void attn_kernel(
    const float* __restrict__ Q, const float* __restrict__ K,
    const float* __restrict__ V, const float* __restrict__ Vpre,
    float* __restrict__ out)
{
    __shared__ __align__(16) ushort Khi[64 * 64], Klo[64 * 64];   // [key][d] ^((key&7)<<3)
    __shared__ __align__(16) ushort VThi[64 * 64], VTlo[64 * 64]; // [d][key] ^((d&7)<<3)
    __shared__ __align__(16) ushort Phi_s[4][16 * 64];            // per-wave [q][key] ^((q&7)<<3)
    __shared__ __align__(16) ushort Plo_s[4][16 * 64];

    const int t    = threadIdx.x;
    const int lane = t & 63;
    const int wv   = t >> 6;                   // wave 0..3 -> q rows wv*16..+15
    const int l15  = lane & 15;
    const int g2   = lane >> 4;                // 0..3

    const int L    = blockIdx.x;
    const int xcd  = L & 7;
    const int slot = L >> 3;                   // 0..95
    const int bh   = xcd * 3 + (slot >> 5);
    const int qb   = slot & 31;
    const int b    = bh / NHEAD;
    const int h    = bh % NHEAD;
    const int i0   = qb * 64;
    const int i    = i0 + wv * 16 + l15;       // this lane's q row (acc column)

    const float* kbase = &K[(size_t)bh * SEQ * HDIM];
    const float* vbase = &V[(size_t)bh * SEQ * HDIM];

    // ---- Q fragments (B-operand), hoisted, hi/lo ----
    short8 qh[2], qlo[2];
    {
        const float* qrow = &Q[((size_t)bh * SEQ + i) * HDIM];
#pragma unroll
        for (int s = 0; s < 2; ++s) {
            float4 a = *(const float4*)&qrow[s * 32 + g2 * 8];
            float4 c = *(const float4*)&qrow[s * 32 + g2 * 8 + 4];
            float qf[8] = {a.x, a.y, a.z, a.w, c.x, c.y, c.z, c.w};
#pragma unroll
            for (int j = 0; j < 8; ++j) {
                ushort hh = bf16_rne(qf[j]);
                qh[s][j]  = (short)hh;
                qlo[s][j] = (short)bf16_rne(qf[j] - bf16_to_f(hh));
            }
        }
    }

    // ---- staging assignment ----
    const int krow = t >> 2;                   // 0..63 (key row)
    const int kc   = (t & 3) * 16;             // d offset, 16 floats
    const int vkp  = t >> 3;                   // 0..31 -> keys 2vkp, 2vkp+1
    const int vdc  = (t & 7) * 8;              // d offset, 8 floats
    float4 kpre[4], vp0[2], vp1[2];

    const int jlo_blk = max(0, i0 - WIN);
    const int jhi_blk = min(SEQ - 1, i0 + 63 + WIN);

    auto LOADT = [&](int jt2) {
        const float* kr = &kbase[(size_t)(jt2 + krow) * HDIM + kc];
        kpre[0] = *(const float4*)&kr[0];
        kpre[1] = *(const float4*)&kr[4];
        kpre[2] = *(const float4*)&kr[8];
        kpre[3] = *(const float4*)&kr[12];
        const float* vr0 = &vbase[(size_t)(jt2 + 2 * vkp) * HDIM + vdc];
        const float* vr1 = &vbase[(size_t)(jt2 + 2 * vkp + 1) * HDIM + vdc];
        vp0[0] = *(const float4*)&vr0[0];
        vp0[1] = *(const float4*)&vr0[4];
        vp1[0] = *(const float4*)&vr1[0];
        vp1[1] = *(const float4*)&vr1[4];
    };
    auto STORET = [&]() {
#pragma unroll
        for (int c = 0; c < 4; ++c) {
            float x0 = kpre[c].x, x1 = kpre[c].y, x2 = kpre[c].z, x3 = kpre[c].w;
            ushort h0 = bf16_rne(x0), h1 = bf16_rne(x1),
                   h2 = bf16_rne(x2), h3 = bf16_rne(x3);
            ushort l0 = bf16_rne(x0 - bf16_to_f(h0)),
                   l1 = bf16_rne(x1 - bf16_to_f(h1)),
                   l2 = bf16_rne(x2 - bf16_to_f(h2)),
                   l3 = bf16_rne(x3 - bf16_to_f(h3));
            int idx = (krow * 64 + kc + c * 4) ^ ((krow & 7) << 3);
            *(uint2*)&Khi[idx] = make_uint2((uint)h0 | ((uint)h1 << 16),
                                            (uint)h2 | ((uint)h3 << 16));
            *(uint2*)&Klo[idx] = make_uint2((uint)l0 | ((uint)l1 << 16),
                                            (uint)l2 | ((uint)l3 << 16));
        }
        float va[8] = {vp0[0].x, vp0[0].y, vp0[0].z, vp0[0].w,
                       vp0[1].x, vp0[1].y, vp0[1].z, vp0[1].w};
        float vb8[8] = {vp1[0].x, vp1[0].y, vp1[0].z, vp1[0].w,
                        vp1[1].x, vp1[1].y, vp1[1].z, vp1[1].w};
#pragma unroll
        for (int j = 0; j < 8; ++j) {
            int d = vdc + j;
            ushort ah = bf16_rne(va[j]), bh2 = bf16_rne(vb8[j]);
            ushort al = bf16_rne(va[j] - bf16_to_f(ah)),
                   bl = bf16_rne(vb8[j] - bf16_to_f(bh2));
            int idx = (d * 64 + 2 * vkp) ^ ((d & 7) << 3);
            *(uint*)&VThi[idx] = (uint)ah | ((uint)bh2 << 16);
            *(uint*)&VTlo[idx] = (uint)al | ((uint)bl << 16);
        }
    };

    float mrun = 0.f, lrun = 0.f;              // mask zeros always in softmax set
    f32x4 ctx[4];
#pragma unroll
    for (int f = 0; f < 4; ++f) ctx[f] = (f32x4){0.f, 0.f, 0.f, 0.f};

    LOADT(jlo_blk);
    STORET();                                   // preload tile 0

    for (int jt = jlo_blk; jt <= jhi_blk; jt += 64) {
        const bool more = (jt + 64) <= jhi_blk;
        if (more) LOADT(jt + 64);               // T14: issue early, write late
        __syncthreads();                        // staged tile visible

        // ---- QK^T: S^T[64 keys][16 q] ----
        f32x4 sacc[4];
#pragma unroll
        for (int f = 0; f < 4; ++f) sacc[f] = (f32x4){0.f, 0.f, 0.f, 0.f};
#pragma unroll
        for (int s = 0; s < 2; ++s) {
            short8 kh[4], kl[4];
#pragma unroll
            for (int f = 0; f < 4; ++f) {
                int row = f * 16 + l15;
                int idx = (row * 64 + s * 32 + g2 * 8) ^ ((row & 7) << 3);
                kh[f] = *(const short8*)&Khi[idx];
                kl[f] = *(const short8*)&Klo[idx];
            }
#pragma unroll
            for (int f = 0; f < 4; ++f) {
                sacc[f] = __builtin_amdgcn_mfma_f32_16x16x32_bf16(kh[f], qh[s],  sacc[f], 0, 0, 0);
                sacc[f] = __builtin_amdgcn_mfma_f32_16x16x32_bf16(kh[f], qlo[s], sacc[f], 0, 0, 0);
                sacc[f] = __builtin_amdgcn_mfma_f32_16x16x32_bf16(kl[f], qh[s],  sacc[f], 0, 0, 0);
            }
        }

        // ---- softmax (lane-local rows; key j = jt + f*16 + g2*4 + r) ----
        float p[4][4];
        float tmax = -1e30f;
#pragma unroll
        for (int f = 0; f < 4; ++f)
#pragma unroll
            for (int r = 0; r < 4; ++r) {
                int j = jt + f * 16 + g2 * 4 + r;
                bool inw = (j >= i - WIN) && (j <= i + WIN);
                float sv_ = inw ? sacc[f][r] : -1e30f;
                p[f][r] = sv_;
                tmax = fmaxf(tmax, sv_);
            }
        tmax = fmaxf(tmax, __shfl_xor(tmax, 16));
        tmax = fmaxf(tmax, __shfl_xor(tmax, 32));
        float m_new = fmaxf(mrun, tmax);
        float resc  = __expf(mrun - m_new);
        float lsum  = 0.f;
#pragma unroll
        for (int f = 0; f < 4; ++f)
#pragma unroll
            for (int r = 0; r < 4; ++r) {
                float pe = __expf(p[f][r] - m_new);
                p[f][r] = pe;
                lsum += pe;
            }
        lsum += __shfl_xor(lsum, 16);
        lsum += __shfl_xor(lsum, 32);
        lrun = lrun * resc + lsum;
        mrun = m_new;
#pragma unroll
        for (int f = 0; f < 4; ++f) {
            ctx[f][0] *= resc; ctx[f][1] *= resc;
            ctx[f][2] *= resc; ctx[f][3] *= resc;
        }

        // ---- P -> bf16 hi/lo into per-wave LDS ([q][key], swizzled) ----
#pragma unroll
        for (int f = 0; f < 4; ++f) {
            ushort h0 = bf16_rne(p[f][0]), h1 = bf16_rne(p[f][1]),
                   h2 = bf16_rne(p[f][2]), h3 = bf16_rne(p[f][3]);
            ushort l0 = bf16_rne(p[f][0] - bf16_to_f(h0)),
                   l1 = bf16_rne(p[f][1] - bf16_to_f(h1)),
                   l2 = bf16_rne(p[f][2] - bf16_to_f(h2)),
                   l3 = bf16_rne(p[f][3] - bf16_to_f(h3));
            int idx = (l15 * 64 + f * 16 + g2 * 4) ^ ((l15 & 7) << 3);
            *(uint2*)&Phi_s[wv][idx] = make_uint2((uint)h0 | ((uint)h1 << 16),
                                                  (uint)h2 | ((uint)h3 << 16));
            *(uint2*)&Plo_s[wv][idx] = make_uint2((uint)l0 | ((uint)l1 << 16),
                                                  (uint)l2 | ((uint)l3 << 16));
        }

        // ---- PV: ctx^T[64 d][16 q] += V^T . P^T ----
#pragma unroll
        for (int s = 0; s < 2; ++s) {
            int pidx = (l15 * 64 + s * 32 + g2 * 8) ^ ((l15 & 7) << 3);
            short8 ph = *(const short8*)&Phi_s[wv][pidx];
            short8 pl = *(const short8*)&Plo_s[wv][pidx];
#pragma unroll
            for (int f = 0; f < 4; ++f) {
                int row = f * 16 + l15;
                int idx = (row * 64 + s * 32 + g2 * 8) ^ ((row & 7) << 3);
                short8 vh = *(const short8*)&VThi[idx];
                short8 vl = *(const short8*)&VTlo[idx];
                ctx[f] = __builtin_amdgcn_mfma_f32_16x16x32_bf16(vh, ph, ctx[f], 0, 0, 0);
                ctx[f] = __builtin_amdgcn_mfma_f32_16x16x32_bf16(vl, ph, ctx[f], 0, 0, 0);
                ctx[f] = __builtin_amdgcn_mfma_f32_16x16x32_bf16(vh, pl, ctx[f], 0, 0, 0);
            }
        }

        __syncthreads();                        // all reads of this tile done
        if (more) STORET();                     // commit prefetched tile
    }

    // ---- out-of-window correction + normalize + store ----
    const int jlo = max(0, i - WIN);
    const int jhi = min(SEQ - 1, i + WIN);
    const int cnt = jhi - jlo + 1;
    const float em   = __expf(-mrun);
    const float ltot = lrun + (float)(SEQ - cnt) * em;
    const float inv  = 1.f / ltot;

    const float* vpT = &Vpre[((size_t)bh * SEQ + (SEQ - 1)) * HDIM];
    const float* vpH = &Vpre[((size_t)bh * SEQ + jhi) * HDIM];
    const float* vpL = &Vpre[((size_t)bh * SEQ + (jlo - 1)) * HDIM];  // read only if jlo>0
    float* orow = &out[((size_t)(b * SEQ + i)) * HIDDEN + h * HDIM];

#pragma unroll
    for (int f = 0; f < 4; ++f) {
        int d0 = f * 16 + g2 * 4;
        float4 tt = *(const float4*)&vpT[d0];
        float4 hh = *(const float4*)&vpH[d0];
        float4 ll = {0.f, 0.f, 0.f, 0.f};
        if (jlo > 0) ll = *(const float4*)&vpL[d0];
        float4 o;
        o.x = (ctx[f][0] + em * (tt.x - hh.x + ll.x)) * inv;
        o.y = (ctx[f][1] + em * (tt.y - hh.y + ll.y)) * inv;
        o.z = (ctx[f][2] + em * (tt.z - hh.z + ll.z)) * inv;
        o.w = (ctx[f][3] + em * (tt.w - hh.w + ll.w)) * inv;
        *(float4*)&orow[d0] = o;
    }
}

// ---------------------------------------------------------------------------
extern "C" void kernel_launch(void* const* d_in, const int* in_sizes, int n_in,
                              void* d_out, int out_size, void* d_ws, size_t ws_size,
                              hipStream_t stream) {
    const float* X  = (const float*)d_in[0];
    const float* Wq = (const float*)d_in[1];
    const float* bq = (const float*)d_in[2];
    const float* Wk = (const float*)d_in[3];
    const float* bk = (const float*)d_in[4];
    const float* Wv = (const float*)d_in[5];
    const float* bv = (const float*)d_in[6];
    float* out = (float*)d_out;

    const size_t NX = (size_t)MTOT * HIDDEN;               // 3,145,728
    const size_t NW = (size_t)HIDDEN * HIDDEN;             // 589,824
    const size_t TEN = (size_t)BATCH * NHEAD * SEQ * HDIM; // 3,145,728

    float* qf   = (float*)d_ws;       // 12.58 MB
    float* kf   = qf + TEN;           // 12.58 MB
    float* vf   = kf + TEN;           // 12.58 MB
    float* vpre = vf + TEN;           // 12.58 MB — ALSO hosts Xhi/Xlo pre-vprefix
    ushort* Xhi = (ushort*)vpre;      //   (proj finishes reading X before vprefix
    ushort* Xlo = Xhi + NX;           //    overwrites this region; stream-ordered)
    ushort* Whi = (ushort*)(vpre + TEN);  // 3.54 MB
    ushort* Wlo = Whi + 3 * NW;           // 3.54 MB -> total 57.4 MB (= R5 proven)

    convert_kernel<<<(int)(NX / 4 / 256), 256, 0, stream>>>(X, Xhi, Xlo, (int)(NX / 4));
    convert_kernel<<<(int)(NW / 4 / 256), 256, 0, stream>>>(Wq, Whi, Wlo, (int)(NW / 4));
    convert_kernel<<<(int)(NW / 4 / 256), 256, 0, stream>>>(Wk, Whi + NW, Wlo + NW, (int)(NW / 4));
    convert_kernel<<<(int)(NW / 4 / 256), 256, 0, stream>>>(Wv, Whi + 2 * NW, Wlo + 2 * NW, (int)(NW / 4));

    proj_mfma_kernel<<<dim3(MTOT / 128, NHEAD, 3), 256, 0, stream>>>(
        Xhi, Xlo, Whi, Wlo, bq, bk, bv, qf, kf, vf);

    vprefix_kernel<<<dim3(BATCH * NHEAD), 256, 0, stream>>>(vf, vpre);

    attn_kernel<<<dim3((SEQ / 64) * BATCH * NHEAD), 256, 0, stream>>>(
        qf, kf, vf, vpre, out);
}

// Round 9
// 379.102 us; speedup vs baseline: 1.1369x; 1.0360x over previous
//
#include <hip/hip_runtime.h>
#include <hip/hip_bf16.h>
#include <cstdint>

// Problem constants (LongformerSelfAttention: B=2, S=2048, M=768, H=12, D=64, W=256, DIL=1)
#define SEQ    2048
#define HIDDEN 768
#define NHEAD  12
#define HDIM   64
#define WIN    256
#define BATCH  2
#define MTOT   (BATCH * SEQ)   // 4096 tokens

typedef __attribute__((ext_vector_type(8))) short short8;   // 8 bf16 = 4 VGPR (MFMA A/B frag)
typedef __attribute__((ext_vector_type(4))) float f32x4;    // MFMA C/D frag

__device__ __forceinline__ ushort bf16_rne(float f) {
    uint u = __float_as_uint(f);
    uint r = u + 0x7FFFu + ((u >> 16) & 1u);   // round-to-nearest-even
    return (ushort)(r >> 16);
}
__device__ __forceinline__ float bf16_to_f(ushort h) {
    return __uint_as_float(((uint)h) << 16);
}

// ---------------------------------------------------------------------------
// Projection GEMM via split-bf16 MFMA — WHICH-FUSED (R9).
// One block computes Q, K, V for its (m-block, head): the X tile is loaded
// and converted ONCE instead of 3x (R4's conversion was 36x-redundant on X).
// Reads fp32 X/W from d_in, converts during LDS staging (R4-proven path —
// pre-converted ws inputs showed an unexplained 15x WRITE amplification in
// R5/R6/R8; open anomaly, design avoids it).
// fp32 outputs [bh][s][d], 64B-segment stores (R4-proven clean: 36.8 MB).
// BM=128, BN=64 (= one head), BK=64, 256 threads = 4 waves 2x2.
// LDS: A 2x16KB + B 2x24KB = 80 KB -> 2 blocks/CU.
// ---------------------------------------------------------------------------
__global__ __launch_bounds__(256) void proj_mfma_kernel(
    const float* __restrict__ X,
    const float* __restrict__ Wq, const float* __restrict__ bq,
    const float* __restrict__ Wk, const float* __restrict__ bk,
    const float* __restrict__ Wv, const float* __restrict__ bv,
    float* __restrict__ Qo, float* __restrict__ Ko, float* __restrict__ Vo)
{
    __shared__ __align__(16) ushort Ahi[128 * 64];
    __shared__ __align__(16) ushort Alo[128 * 64];
    __shared__ __align__(16) ushort Bhi[3 * 64 * 64];
    __shared__ __align__(16) ushort Blo[3 * 64 * 64];

    const int t  = threadIdx.x;
    const int m0 = blockIdx.x * 128;
    const int h  = blockIdx.y;
    const int n0 = h * 64;

    const int w    = t >> 6;
    const int lane = t & 63;
    const int wr   = w >> 1;
    const int wc   = w & 1;
    const int lr   = lane & 15;
    const int lk   = lane >> 4;

    const float* const Wp[3] = {Wq, Wk, Wv};

    f32x4 acc[3][4][2];
#pragma unroll
    for (int q = 0; q < 3; ++q)
#pragma unroll
        for (int i = 0; i < 4; ++i)
#pragma unroll
            for (int j = 0; j < 2; ++j) acc[q][i][j] = (f32x4){0.f, 0.f, 0.f, 0.f};

    for (int k0 = 0; k0 < HIDDEN; k0 += 64) {
        __syncthreads();   // previous iteration's frag reads done
        // ---- stage + convert A tile once: 128 rows x 64 k (8 float4/thread) ----
#pragma unroll
        for (int i = 0; i < 8; ++i) {
            int id  = t + i * 256;
            int row = id >> 4;
            int c4  = id & 15;
            const float4 xv = *(const float4*)&X[(size_t)(m0 + row) * HIDDEN + k0 + c4 * 4];
            ushort h0 = bf16_rne(xv.x), h1 = bf16_rne(xv.y),
                   h2 = bf16_rne(xv.z), h3 = bf16_rne(xv.w);
            ushort l0 = bf16_rne(xv.x - bf16_to_f(h0)),
                   l1 = bf16_rne(xv.y - bf16_to_f(h1)),
                   l2 = bf16_rne(xv.z - bf16_to_f(h2)),
                   l3 = bf16_rne(xv.w - bf16_to_f(h3));
            int idx = (row * 64 + c4 * 4) ^ ((row & 7) << 3);
            *(uint2*)&Ahi[idx] = make_uint2((uint)h0 | ((uint)h1 << 16),
                                            (uint)h2 | ((uint)h3 << 16));
            *(uint2*)&Alo[idx] = make_uint2((uint)l0 | ((uint)l1 << 16),
                                            (uint)l2 | ((uint)l3 << 16));
        }
        // ---- stage + convert B tiles for all 3 which ----
#pragma unroll
        for (int q = 0; q < 3; ++q) {
            const float* __restrict__ Wb = Wp[q];
#pragma unroll
            for (int i = 0; i < 4; ++i) {
                int id  = t + i * 256;
                int row = id >> 4;
                int c4  = id & 15;
                const float4 wv4 = *(const float4*)&Wb[(size_t)(n0 + row) * HIDDEN + k0 + c4 * 4];
                ushort h0 = bf16_rne(wv4.x), h1 = bf16_rne(wv4.y),
                       h2 = bf16_rne(wv4.z), h3 = bf16_rne(wv4.w);
                ushort l0 = bf16_rne(wv4.x - bf16_to_f(h0)),
                       l1 = bf16_rne(wv4.y - bf16_to_f(h1)),
                       l2 = bf16_rne(wv4.z - bf16_to_f(h2)),
                       l3 = bf16_rne(wv4.w - bf16_to_f(h3));
                int idx = q * 4096 + ((row * 64 + c4 * 4) ^ ((row & 7) << 3));
                *(uint2*)&Bhi[idx] = make_uint2((uint)h0 | ((uint)h1 << 16),
                                                (uint)h2 | ((uint)h3 << 16));
                *(uint2*)&Blo[idx] = make_uint2((uint)l0 | ((uint)l1 << 16),
                                                (uint)l2 | ((uint)l3 << 16));
            }
        }
        __syncthreads();

        // ---- MFMA: A frags loaded once per s, reused across 3 which ----
#pragma unroll
        for (int s = 0; s < 2; ++s) {
            short8 ah[4], al[4];
#pragma unroll
            for (int fm = 0; fm < 4; ++fm) {
                int row = wr * 64 + fm * 16 + lr;
                int idx = (row * 64 + s * 32 + lk * 8) ^ ((row & 7) << 3);
                ah[fm] = *(const short8*)&Ahi[idx];
                al[fm] = *(const short8*)&Alo[idx];
            }
#pragma unroll
            for (int q = 0; q < 3; ++q) {
                short8 bh2[2], bl2[2];
#pragma unroll
                for (int fn = 0; fn < 2; ++fn) {
                    int row = wc * 32 + fn * 16 + lr;
                    int idx = q * 4096 + ((row * 64 + s * 32 + lk * 8) ^ ((row & 7) << 3));
                    bh2[fn] = *(const short8*)&Bhi[idx];
                    bl2[fn] = *(const short8*)&Blo[idx];
                }
#pragma unroll
                for (int fm = 0; fm < 4; ++fm)
#pragma unroll
                    for (int fn = 0; fn < 2; ++fn) {
                        acc[q][fm][fn] = __builtin_amdgcn_mfma_f32_16x16x32_bf16(
                            ah[fm], bh2[fn], acc[q][fm][fn], 0, 0, 0);
                        acc[q][fm][fn] = __builtin_amdgcn_mfma_f32_16x16x32_bf16(
                            ah[fm], bl2[fn], acc[q][fm][fn], 0, 0, 0);
                        acc[q][fm][fn] = __builtin_amdgcn_mfma_f32_16x16x32_bf16(
                            al[fm], bh2[fn], acc[q][fm][fn], 0, 0, 0);
                    }
            }
        }
    }

    // ---- epilogue (R4-proven): fp32 stores, 64B contiguous per 16-lane group ----
#pragma unroll
    for (int q = 0; q < 3; ++q) {
        const float* __restrict__ bias = (q == 0) ? bq : (q == 1) ? bk : bv;
        float* __restrict__ out        = (q == 0) ? Qo : (q == 1) ? Ko : Vo;
        const float scale = (q == 0) ? 0.125f : 1.0f;
#pragma unroll
        for (int fn = 0; fn < 2; ++fn) {
            int d = wc * 32 + fn * 16 + lr;
            float bval = bias[n0 + d];
#pragma unroll
            for (int fm = 0; fm < 4; ++fm) {
#pragma unroll
                for (int r = 0; r < 4; ++r) {
                    int m  = m0 + wr * 64 + fm * 16 + lk * 4 + r;
                    int bb = m >> 11;
                    int ss = m & (SEQ - 1);
                    out[(((size_t)(bb * NHEAD + h) * SEQ) + ss) * HDIM + d] =
                        (acc[q][fm][fn][r] + bval) * scale;
                }
            }
        }
    }
}

// ---------------------------------------------------------------------------
// Prefix sum of V along sequence per (b,h,d) (R4 verbatim; V fp32 [bh][s][d]).
// ---------------------------------------------------------------------------
__global__ __launch_bounds__(256) void vprefix_kernel(
    const float* __restrict__ V, float* __restrict__ Vpre)
{
    const int bh    = blockIdx.x;
    const int d     = threadIdx.x & 63;
    const int chunk = threadIdx.x >> 6;
    const float* vb = &V[(size_t)bh * SEQ * HDIM];
    float* pb       = &Vpre[(size_t)bh * SEQ * HDIM];

    __shared__ float csum[4][64];
    const int s0 = chunk * 512;
    float sum = 0.f;
    for (int s = s0; s < s0 + 512; ++s) sum += vb[(size_t)s * HDIM + d];
    csum[chunk][d] = sum;
    __syncthreads();
    float run = 0.f;
    for (int c = 0; c < chunk; ++c) run += csum[c][d];
    for (int s = s0; s < s0 + 512; ++s) {
        run += vb[(size_t)s * HDIM + d];
        pb[(size_t)s * HDIM + d] = run;
    }
}

// ---------------------------------------------------------------------------
// Banded attention v5 — R4 core (split-bf16 MFMA, swapped operands, lane-local
// softmax) with QBLK=128 / 512 threads / 8 waves: K/V staging+conversion
// redundancy drops 9x -> ~5.5x (-44% staging work). Leading fully-masked
// tiles for high-q waves are exact no-ops (p=0, m stays 0) — bit-identical.
// LDS: K/V 32KB + P 32KB = 64KB -> 2 blocks/CU.
// ---------------------------------------------------------------------------
__global__ __launch_bounds__(512, 2) void attn_kernel(
    const float* __restrict__ Q, const float* __restrict__ K,
    const float* __restrict__ V, const float* __restrict__ Vpre,
    float* __restrict__ out)
{
    __shared__ __align__(16) ushort Khi[64 * 64], Klo[64 * 64];   // [key][d] ^((key&7)<<3)
    __shared__ __align__(16) ushort VThi[64 * 64], VTlo[64 * 64]; // [d][key] ^((d&7)<<3)
    __shared__ __align__(16) ushort Phi_s[8][16 * 64];            // per-wave [q][key] ^((q&7)<<3)
    __shared__ __align__(16) ushort Plo_s[8][16 * 64];

    const int t    = threadIdx.x;
    const int lane = t & 63;
    const int wv   = t >> 6;                   // wave 0..7 -> q rows wv*16..+15
    const int l15  = lane & 15;
    const int g2   = lane >> 4;                // 0..3

    const int L    = blockIdx.x;               // 384 blocks
    const int xcd  = L & 7;
    const int slot = L >> 3;                   // 0..47
    const int bh   = xcd * 3 + (slot >> 4);    // 0..23
    const int qb   = slot & 15;                // 0..15
    const int b    = bh / NHEAD;
    const int h    = bh % NHEAD;
    const int i0   = qb * 128;
    const int i    = i0 + wv * 16 + l15;       // this lane's q row (acc column)

    const float* kbase = &K[(size_t)bh * SEQ * HDIM];
    const float* vbase = &V[(size_t)bh * SEQ * HDIM];

    // ---- Q fragments (B-operand), hoisted, hi/lo ----
    short8 qh[2], qlo[2];
    {
        const float* qrow = &Q[((size_t)bh * SEQ + i) * HDIM];
#pragma unroll
        for (int s = 0; s < 2; ++s) {
            float4 a = *(const float4*)&qrow[s * 32 + g2 * 8];
            float4 c = *(const float4*)&qrow[s * 32 + g2 * 8 + 4];
            float qf[8] = {a.x, a.y, a.z, a.w, c.x, c.y, c.z, c.w};
#pragma unroll
            for (int j = 0; j < 8; ++j) {
                ushort hh = bf16_rne(qf[j]);
                qh[s][j]  = (short)hh;
                qlo[s][j] = (short)bf16_rne(qf[j] - bf16_to_f(hh));
            }
        }
    }

    // ---- staging assignment (512 threads; 8 K-floats + 8 V-floats each) ----
    const int krow = t >> 3;                   // 0..63 (key row)
    const int kc   = (t & 7) * 8;              // d offset, 8 floats
    const int vkp  = t >> 4;                   // 0..31 -> keys 2vkp, 2vkp+1
    const int vdc  = (t & 15) * 4;             // d offset, 4 floats
    float4 kpre[2], vp0, vp1;

    const int jlo_blk = max(0, i0 - WIN);
    const int jhi_blk = min(SEQ - 1, i0 + 127 + WIN);

    auto LOADT = [&](int jt2) {
        const float* kr = &kbase[(size_t)(jt2 + krow) * HDIM + kc];
        kpre[0] = *(const float4*)&kr[0];
        kpre[1] = *(const float4*)&kr[4];
        vp0 = *(const float4*)&vbase[(size_t)(jt2 + 2 * vkp) * HDIM + vdc];
        vp1 = *(const float4*)&vbase[(size_t)(jt2 + 2 * vkp + 1) * HDIM + vdc];
    };
    auto STORET = [&]() {
#pragma unroll
        for (int c = 0; c < 2; ++c) {
            float x0 = kpre[c].x, x1 = kpre[c].y, x2 = kpre[c].z, x3 = kpre[c].w;
            ushort h0 = bf16_rne(x0), h1 = bf16_rne(x1),
                   h2 = bf16_rne(x2), h3 = bf16_rne(x3);
            ushort l0 = bf16_rne(x0 - bf16_to_f(h0)),
                   l1 = bf16_rne(x1 - bf16_to_f(h1)),
                   l2 = bf16_rne(x2 - bf16_to_f(h2)),
                   l3 = bf16_rne(x3 - bf16_to_f(h3));
            int idx = (krow * 64 + kc + c * 4) ^ ((krow & 7) << 3);
            *(uint2*)&Khi[idx] = make_uint2((uint)h0 | ((uint)h1 << 16),
                                            (uint)h2 | ((uint)h3 << 16));
            *(uint2*)&Klo[idx] = make_uint2((uint)l0 | ((uint)l1 << 16),
                                            (uint)l2 | ((uint)l3 << 16));
        }
        float va[4] = {vp0.x, vp0.y, vp0.z, vp0.w};
        float vb4[4] = {vp1.x, vp1.y, vp1.z, vp1.w};
#pragma unroll
        for (int j = 0; j < 4; ++j) {
            int d = vdc + j;
            ushort ah = bf16_rne(va[j]), bh2 = bf16_rne(vb4[j]);
            ushort al = bf16_rne(va[j] - bf16_to_f(ah)),
                   bl = bf16_rne(vb4[j] - bf16_to_f(bh2));
            int idx = (d * 64 + 2 * vkp) ^ ((d & 7) << 3);
            *(uint*)&VThi[idx] = (uint)ah | ((uint)bh2 << 16);
            *(uint*)&VTlo[idx] = (uint)al | ((uint)bl << 16);
        }
    };

    float mrun = 0.f, lrun = 0.f;              // mask zeros always in softmax set
    f32x4 ctx[4];
#pragma unroll
    for (int f = 0; f < 4; ++f) ctx[f] = (f32x4){0.f, 0.f, 0.f, 0.f};

    LOADT(jlo_blk);
    STORET();                                   // preload tile 0

    for (int jt = jlo_blk; jt <= jhi_blk; jt += 64) {
        const bool more = (jt + 64) <= jhi_blk;
        if (more) LOADT(jt + 64);               // T14: issue early, write late
        __syncthreads();                        // staged tile visible

        // ---- QK^T: S^T[64 keys][16 q] ----
        f32x4 sacc[4];
#pragma unroll
        for (int f = 0; f < 4; ++f) sacc[f] = (f32x4){0.f, 0.f, 0.f, 0.f};
#pragma unroll
        for (int s = 0; s < 2; ++s) {
            short8 kh[4], kl[4];
#pragma unroll
            for (int f = 0; f < 4; ++f) {
                int row = f * 16 + l15;
                int idx = (row * 64 + s * 32 + g2 * 8) ^ ((row & 7) << 3);
                kh[f] = *(const short8*)&Khi[idx];
                kl[f] = *(const short8*)&Klo[idx];
            }
#pragma unroll
            for (int f = 0; f < 4; ++f) {
                sacc[f] = __builtin_amdgcn_mfma_f32_16x16x32_bf16(kh[f], qh[s],  sacc[f], 0, 0, 0);
                sacc[f] = __builtin_amdgcn_mfma_f32_16x16x32_bf16(kh[f], qlo[s], sacc[f], 0, 0, 0);
                sacc[f] = __builtin_amdgcn_mfma_f32_16x16x32_bf16(kl[f], qh[s],  sacc[f], 0, 0, 0);
            }
        }

        // ---- softmax (lane-local rows; key j = jt + f*16 + g2*4 + r) ----
        float p[4][4];
        float tmax = -1e30f;
#pragma unroll
        for (int f = 0; f < 4; ++f)
#pragma unroll
            for (int r = 0; r < 4; ++r) {
                int j = jt + f * 16 + g2 * 4 + r;
                bool inw = (j >= i - WIN) && (j <= i + WIN);
                float sv_ = inw ? sacc[f][r] : -1e30f;
                p[f][r] = sv_;
                tmax = fmaxf(tmax, sv_);
            }
        tmax = fmaxf(tmax, __shfl_xor(tmax, 16));
        tmax = fmaxf(tmax, __shfl_xor(tmax, 32));
        float m_new = fmaxf(mrun, tmax);
        float resc  = __expf(mrun - m_new);
        float lsum  = 0.f;
#pragma unroll
        for (int f = 0; f < 4; ++f)
#pragma unroll
            for (int r = 0; r < 4; ++r) {
                float pe = __expf(p[f][r] - m_new);
                p[f][r] = pe;
                lsum += pe;
            }
        lsum += __shfl_xor(lsum, 16);
        lsum += __shfl_xor(lsum, 32);
        lrun = lrun * resc + lsum;
        mrun = m_new;
#pragma unroll
        for (int f = 0; f < 4; ++f) {
            ctx[f][0] *= resc; ctx[f][1] *= resc;
            ctx[f][2] *= resc; ctx[f][3] *= resc;
        }

        // ---- P -> bf16 hi/lo into per-wave LDS ([q][key], swizzled) ----
#pragma unroll
        for (int f = 0; f < 4; ++f) {
            ushort h0 = bf16_rne(p[f][0]), h1 = bf16_rne(p[f][1]),
                   h2 = bf16_rne(p[f][2]), h3 = bf16_rne(p[f][3]);
            ushort l0 = bf16_rne(p[f][0] - bf16_to_f(h0)),
                   l1 = bf16_rne(p[f][1] - bf16_to_f(h1)),
                   l2 = bf16_rne(p[f][2] - bf16_to_f(h2)),
                   l3 = bf16_rne(p[f][3] - bf16_to_f(h3));
            int idx = (l15 * 64 + f * 16 + g2 * 4) ^ ((l15 & 7) << 3);
            *(uint2*)&Phi_s[wv][idx] = make_uint2((uint)h0 | ((uint)h1 << 16),
                                                  (uint)h2 | ((uint)h3 << 16));
            *(uint2*)&Plo_s[wv][idx] = make_uint2((uint)l0 | ((uint)l1 << 16),
                                                  (uint)l2 | ((uint)l3 << 16));
        }

        // ---- PV: ctx^T[64 d][16 q] += V^T . P^T ----
#pragma unroll
        for (int s = 0; s < 2; ++s) {
            int pidx = (l15 * 64 + s * 32 + g2 * 8) ^ ((l15 & 7) << 3);
            short8 ph = *(const short8*)&Phi_s[wv][pidx];
            short8 pl = *(const short8*)&Plo_s[wv][pidx];
#pragma unroll
            for (int f = 0; f < 4; ++f) {
                int row = f * 16 + l15;
                int idx = (row * 64 + s * 32 + g2 * 8) ^ ((row & 7) << 3);
                short8 vh = *(const short8*)&VThi[idx];
                short8 vl = *(const short8*)&VTlo[idx];
                ctx[f] = __builtin_amdgcn_mfma_f32_16x16x32_bf16(vh, ph, ctx[f], 0, 0, 0);
                ctx[f] = __builtin_amdgcn_mfma_f32_16x16x32_bf16(vl, ph, ctx[f], 0, 0, 0);
                ctx[f] = __builtin_amdgcn_mfma_f32_16x16x32_bf16(vh, pl, ctx[f], 0, 0, 0);
            }
        }

        __syncthreads();                        // all reads of this tile done
        if (more) STORET();                     // commit prefetched tile
    }

    // ---- out-of-window correction + normalize + store ----
    const int jlo = max(0, i - WIN);
    const int jhi = min(SEQ - 1, i + WIN);
    const int cnt = jhi - jlo + 1;
    const float em   = __expf(-mrun);
    const float ltot = lrun + (float)(SEQ - cnt) * em;
    const float inv  = 1.f / ltot;

    const float* vpT = &Vpre[((size_t)bh * SEQ + (SEQ - 1)) * HDIM];
    const float* vpH = &Vpre[((size_t)bh * SEQ + jhi) * HDIM];
    const float* vpL = &Vpre[((size_t)bh * SEQ + (jlo - 1)) * HDIM];  // read only if jlo>0
    float* orow = &out[((size_t)(b * SEQ + i)) * HIDDEN + h * HDIM];

#pragma unroll
    for (int f = 0; f < 4; ++f) {
        int d0 = f * 16 + g2 * 4;
        float4 tt = *(const float4*)&vpT[d0];
        float4 hh = *(const float4*)&vpH[d0];
        float4 ll = {0.f, 0.f, 0.f, 0.f};
        if (jlo > 0) ll = *(const float4*)&vpL[d0];
        float4 o;
        o.x = (ctx[f][0] + em * (tt.x - hh.x + ll.x)) * inv;
        o.y = (ctx[f][1] + em * (tt.y - hh.y + ll.y)) * inv;
        o.z = (ctx[f][2] + em * (tt.z - hh.z + ll.z)) * inv;
        o.w = (ctx[f][3] + em * (tt.w - hh.w + ll.w)) * inv;
        *(float4*)&orow[d0] = o;
    }
}

// ---------------------------------------------------------------------------
extern "C" void kernel_launch(void* const* d_in, const int* in_sizes, int n_in,
                              void* d_out, int out_size, void* d_ws, size_t ws_size,
                              hipStream_t stream) {
    const float* X  = (const float*)d_in[0];
    const float* Wq = (const float*)d_in[1];
    const float* bq = (const float*)d_in[2];
    const float* Wk = (const float*)d_in[3];
    const float* bk = (const float*)d_in[4];
    const float* Wv = (const float*)d_in[5];
    const float* bv = (const float*)d_in[6];
    float* out = (float*)d_out;

    const size_t TEN = (size_t)BATCH * NHEAD * SEQ * HDIM;  // 3,145,728 floats
    float* qf   = (float*)d_ws;
    float* kf   = qf + TEN;
    float* vf   = kf + TEN;
    float* vpre = vf + TEN;   // 50.3 MB of ws total (R4-proven footprint)

    proj_mfma_kernel<<<dim3(MTOT / 128, NHEAD), 256, 0, stream>>>(
        X, Wq, bq, Wk, bk, Wv, bv, qf, kf, vf);
    vprefix_kernel<<<dim3(BATCH * NHEAD), 256, 0, stream>>>(vf, vpre);
    attn_kernel<<<dim3((SEQ / 128) * BATCH * NHEAD), 512, 0, stream>>>(
        qf, kf, vf, vpre, out);
}

// Round 10
// 244.093 us; speedup vs baseline: 1.7658x; 1.5531x over previous
//
#include <hip/hip_runtime.h>
#include <hip/hip_bf16.h>
#include <cstdint>

// Problem constants (LongformerSelfAttention: B=2, S=2048, M=768, H=12, D=64, W=256, DIL=1)
#define SEQ    2048
#define HIDDEN 768
#define NHEAD  12
#define HDIM   64
#define WIN    256
#define BATCH  2
#define MTOT   (BATCH * SEQ)   // 4096 tokens

typedef __attribute__((ext_vector_type(8))) short short8;   // 8 bf16 = 4 VGPR (MFMA A/B frag)
typedef __attribute__((ext_vector_type(4))) float f32x4;    // MFMA C/D frag

__device__ __forceinline__ ushort bf16_rne(float f) {
    uint u = __float_as_uint(f);
    uint r = u + 0x7FFFu + ((u >> 16) & 1u);   // round-to-nearest-even
    return (ushort)(r >> 16);
}
__device__ __forceinline__ float bf16_to_f(ushort h) {
    return __uint_as_float(((uint)h) << 16);
}

// ---------------------------------------------------------------------------
// Projection GEMM via split-bf16 MFMA — R4 VERBATIM (proven 96 us).
// R9 lesson: which-fusion cut conversion work but dropped the grid to 384
// blocks (1.5 waves/SIMD) -> latency-starved at 222+ us with all pipes idle.
// Parallelism (1152 blocks) beats conversion amortization here.
// In-kernel fp32->hi/lo conversion during staging; fp32 outputs [bh][s][d]
// via 64B-segment stores (WRITE_SIZE 36.8 MB, clean).
// ---------------------------------------------------------------------------
__global__ __launch_bounds__(256) void proj_mfma_kernel(
    const float* __restrict__ X,
    const float* __restrict__ Wq, const float* __restrict__ bq,
    const float* __restrict__ Wk, const float* __restrict__ bk,
    const float* __restrict__ Wv, const float* __restrict__ bv,
    float* __restrict__ Qo, float* __restrict__ Ko, float* __restrict__ Vo)
{
    const int which = blockIdx.z;
    const float* __restrict__ W    = (which == 0) ? Wq : (which == 1) ? Wk : Wv;
    const float* __restrict__ bias = (which == 0) ? bq : (which == 1) ? bk : bv;
    float* __restrict__ out        = (which == 0) ? Qo : (which == 1) ? Ko : Vo;
    const float scale = (which == 0) ? 0.125f : 1.0f;

    __shared__ __align__(16) ushort Ahi[128 * 64];
    __shared__ __align__(16) ushort Alo[128 * 64];
    __shared__ __align__(16) ushort Bhi[64 * 64];
    __shared__ __align__(16) ushort Blo[64 * 64];

    const int t  = threadIdx.x;
    const int m0 = blockIdx.x * 128;
    const int h  = blockIdx.y;
    const int n0 = h * 64;

    const int w    = t >> 6;
    const int lane = t & 63;
    const int wr   = w >> 1;
    const int wc   = w & 1;
    const int lr   = lane & 15;
    const int lk   = lane >> 4;

    f32x4 acc[4][2];
#pragma unroll
    for (int i = 0; i < 4; ++i)
#pragma unroll
        for (int j = 0; j < 2; ++j) acc[i][j] = (f32x4){0.f, 0.f, 0.f, 0.f};

    for (int k0 = 0; k0 < HIDDEN; k0 += 64) {
        __syncthreads();
#pragma unroll
        for (int i = 0; i < 8; ++i) {
            int id  = t + i * 256;
            int row = id >> 4;
            int c4  = id & 15;
            const float4 xv = *(const float4*)&X[(size_t)(m0 + row) * HIDDEN + k0 + c4 * 4];
            ushort h0 = bf16_rne(xv.x), h1 = bf16_rne(xv.y),
                   h2 = bf16_rne(xv.z), h3 = bf16_rne(xv.w);
            ushort l0 = bf16_rne(xv.x - bf16_to_f(h0)),
                   l1 = bf16_rne(xv.y - bf16_to_f(h1)),
                   l2 = bf16_rne(xv.z - bf16_to_f(h2)),
                   l3 = bf16_rne(xv.w - bf16_to_f(h3));
            int idx = (row * 64 + c4 * 4) ^ ((row & 7) << 3);
            *(uint2*)&Ahi[idx] = make_uint2((uint)h0 | ((uint)h1 << 16),
                                            (uint)h2 | ((uint)h3 << 16));
            *(uint2*)&Alo[idx] = make_uint2((uint)l0 | ((uint)l1 << 16),
                                            (uint)l2 | ((uint)l3 << 16));
        }
#pragma unroll
        for (int i = 0; i < 4; ++i) {
            int id  = t + i * 256;
            int row = id >> 4;
            int c4  = id & 15;
            const float4 wv4 = *(const float4*)&W[(size_t)(n0 + row) * HIDDEN + k0 + c4 * 4];
            ushort h0 = bf16_rne(wv4.x), h1 = bf16_rne(wv4.y),
                   h2 = bf16_rne(wv4.z), h3 = bf16_rne(wv4.w);
            ushort l0 = bf16_rne(wv4.x - bf16_to_f(h0)),
                   l1 = bf16_rne(wv4.y - bf16_to_f(h1)),
                   l2 = bf16_rne(wv4.z - bf16_to_f(h2)),
                   l3 = bf16_rne(wv4.w - bf16_to_f(h3));
            int idx = (row * 64 + c4 * 4) ^ ((row & 7) << 3);
            *(uint2*)&Bhi[idx] = make_uint2((uint)h0 | ((uint)h1 << 16),
                                            (uint)h2 | ((uint)h3 << 16));
            *(uint2*)&Blo[idx] = make_uint2((uint)l0 | ((uint)l1 << 16),
                                            (uint)l2 | ((uint)l3 << 16));
        }
        __syncthreads();

#pragma unroll
        for (int s = 0; s < 2; ++s) {
            short8 ah[4], al[4], bh2[2], bl2[2];
#pragma unroll
            for (int fm = 0; fm < 4; ++fm) {
                int row = wr * 64 + fm * 16 + lr;
                int idx = (row * 64 + s * 32 + lk * 8) ^ ((row & 7) << 3);
                ah[fm] = *(const short8*)&Ahi[idx];
                al[fm] = *(const short8*)&Alo[idx];
            }
#pragma unroll
            for (int fn = 0; fn < 2; ++fn) {
                int row = wc * 32 + fn * 16 + lr;
                int idx = (row * 64 + s * 32 + lk * 8) ^ ((row & 7) << 3);
                bh2[fn] = *(const short8*)&Bhi[idx];
                bl2[fn] = *(const short8*)&Blo[idx];
            }
#pragma unroll
            for (int fm = 0; fm < 4; ++fm)
#pragma unroll
                for (int fn = 0; fn < 2; ++fn) {
                    acc[fm][fn] = __builtin_amdgcn_mfma_f32_16x16x32_bf16(
                        ah[fm], bh2[fn], acc[fm][fn], 0, 0, 0);
                    acc[fm][fn] = __builtin_amdgcn_mfma_f32_16x16x32_bf16(
                        ah[fm], bl2[fn], acc[fm][fn], 0, 0, 0);
                    acc[fm][fn] = __builtin_amdgcn_mfma_f32_16x16x32_bf16(
                        al[fm], bh2[fn], acc[fm][fn], 0, 0, 0);
                }
        }
    }

    // ---- epilogue: fp32 stores, 64B contiguous per 16-lane group ----
#pragma unroll
    for (int fn = 0; fn < 2; ++fn) {
        int d = wc * 32 + fn * 16 + lr;
        float bval = bias[n0 + d];
#pragma unroll
        for (int fm = 0; fm < 4; ++fm) {
#pragma unroll
            for (int r = 0; r < 4; ++r) {
                int m  = m0 + wr * 64 + fm * 16 + lk * 4 + r;
                int bb = m >> 11;
                int ss = m & (SEQ - 1);
                out[(((size_t)(bb * NHEAD + h) * SEQ) + ss) * HDIM + d] =
                    (acc[fm][fn][r] + bval) * scale;
            }
        }
    }
}

// ---------------------------------------------------------------------------
// Prefix sum of V along sequence per (b,h,d) (R4 verbatim).
// ---------------------------------------------------------------------------
__global__ __launch_bounds__(256) void vprefix_kernel(
    const float* __restrict__ V, float* __restrict__ Vpre)
{
    const int bh    = blockIdx.x;
    const int d     = threadIdx.x & 63;
    const int chunk = threadIdx.x >> 6;
    const float* vb = &V[(size_t)bh * SEQ * HDIM];
    float* pb       = &Vpre[(size_t)bh * SEQ * HDIM];

    __shared__ float csum[4][64];
    const int s0 = chunk * 512;
    float sum = 0.f;
    for (int s = s0; s < s0 + 512; ++s) sum += vb[(size_t)s * HDIM + d];
    csum[chunk][d] = sum;
    __syncthreads();
    float run = 0.f;
    for (int c = 0; c < chunk; ++c) run += csum[c][d];
    for (int s = s0; s < s0 + 512; ++s) {
        run += vb[(size_t)s * HDIM + d];
        pb[(size_t)s * HDIM + d] = run;
    }
}

// ---------------------------------------------------------------------------
// Banded attention (R9 verbatim — QBLK=128, 512 threads, 8 waves; split-bf16
// MFMA, swapped operands, lane-local softmax, Vpre mask correction).
// ---------------------------------------------------------------------------
__global__ __launch_bounds__(512, 2) void attn_kernel(
    const float* __restrict__ Q, const float* __restrict__ K,
    const float* __restrict__ V, const float* __restrict__ Vpre,
    float* __restrict__ out)
{
    __shared__ __align__(16) ushort Khi[64 * 64], Klo[64 * 64];   // [key][d] ^((key&7)<<3)
    __shared__ __align__(16) ushort VThi[64 * 64], VTlo[64 * 64]; // [d][key] ^((d&7)<<3)
    __shared__ __align__(16) ushort Phi_s[8][16 * 64];            // per-wave [q][key] ^((q&7)<<3)
    __shared__ __align__(16) ushort Plo_s[8][16 * 64];

    const int t    = threadIdx.x;
    const int lane = t & 63;
    const int wv   = t >> 6;                   // wave 0..7 -> q rows wv*16..+15
    const int l15  = lane & 15;
    const int g2   = lane >> 4;                // 0..3

    const int L    = blockIdx.x;               // 384 blocks
    const int xcd  = L & 7;
    const int slot = L >> 3;                   // 0..47
    const int bh   = xcd * 3 + (slot >> 4);    // 0..23
    const int qb   = slot & 15;                // 0..15
    const int b    = bh / NHEAD;
    const int h    = bh % NHEAD;
    const int i0   = qb * 128;
    const int i    = i0 + wv * 16 + l15;       // this lane's q row (acc column)

    const float* kbase = &K[(size_t)bh * SEQ * HDIM];
    const float* vbase = &V[(size_t)bh * SEQ * HDIM];

    // ---- Q fragments (B-operand), hoisted, hi/lo ----
    short8 qh[2], qlo[2];
    {
        const float* qrow = &Q[((size_t)bh * SEQ + i) * HDIM];
#pragma unroll
        for (int s = 0; s < 2; ++s) {
            float4 a = *(const float4*)&qrow[s * 32 + g2 * 8];
            float4 c = *(const float4*)&qrow[s * 32 + g2 * 8 + 4];
            float qf[8] = {a.x, a.y, a.z, a.w, c.x, c.y, c.z, c.w};
#pragma unroll
            for (int j = 0; j < 8; ++j) {
                ushort hh = bf16_rne(qf[j]);
                qh[s][j]  = (short)hh;
                qlo[s][j] = (short)bf16_rne(qf[j] - bf16_to_f(hh));
            }
        }
    }

    // ---- staging assignment (512 threads; 8 K-floats + 8 V-floats each) ----
    const int krow = t >> 3;                   // 0..63 (key row)
    const int kc   = (t & 7) * 8;              // d offset, 8 floats
    const int vkp  = t >> 4;                   // 0..31 -> keys 2vkp, 2vkp+1
    const int vdc  = (t & 15) * 4;             // d offset, 4 floats
    float4 kpre[2], vp0, vp1;

    const int jlo_blk = max(0, i0 - WIN);
    const int jhi_blk = min(SEQ - 1, i0 + 127 + WIN);

    auto LOADT = [&](int jt2) {
        const float* kr = &kbase[(size_t)(jt2 + krow) * HDIM + kc];
        kpre[0] = *(const float4*)&kr[0];
        kpre[1] = *(const float4*)&kr[4];
        vp0 = *(const float4*)&vbase[(size_t)(jt2 + 2 * vkp) * HDIM + vdc];
        vp1 = *(const float4*)&vbase[(size_t)(jt2 + 2 * vkp + 1) * HDIM + vdc];
    };
    auto STORET = [&]() {
#pragma unroll
        for (int c = 0; c < 2; ++c) {
            float x0 = kpre[c].x, x1 = kpre[c].y, x2 = kpre[c].z, x3 = kpre[c].w;
            ushort h0 = bf16_rne(x0), h1 = bf16_rne(x1),
                   h2 = bf16_rne(x2), h3 = bf16_rne(x3);
            ushort l0 = bf16_rne(x0 - bf16_to_f(h0)),
                   l1 = bf16_rne(x1 - bf16_to_f(h1)),
                   l2 = bf16_rne(x2 - bf16_to_f(h2)),
                   l3 = bf16_rne(x3 - bf16_to_f(h3));
            int idx = (krow * 64 + kc + c * 4) ^ ((krow & 7) << 3);
            *(uint2*)&Khi[idx] = make_uint2((uint)h0 | ((uint)h1 << 16),
                                            (uint)h2 | ((uint)h3 << 16));
            *(uint2*)&Klo[idx] = make_uint2((uint)l0 | ((uint)l1 << 16),
                                            (uint)l2 | ((uint)l3 << 16));
        }
        float va[4] = {vp0.x, vp0.y, vp0.z, vp0.w};
        float vb4[4] = {vp1.x, vp1.y, vp1.z, vp1.w};
#pragma unroll
        for (int j = 0; j < 4; ++j) {
            int d = vdc + j;
            ushort ah = bf16_rne(va[j]), bh2 = bf16_rne(vb4[j]);
            ushort al = bf16_rne(va[j] - bf16_to_f(ah)),
                   bl = bf16_rne(vb4[j] - bf16_to_f(bh2));
            int idx = (d * 64 + 2 * vkp) ^ ((d & 7) << 3);
            *(uint*)&VThi[idx] = (uint)ah | ((uint)bh2 << 16);
            *(uint*)&VTlo[idx] = (uint)al | ((uint)bl << 16);
        }
    };

    float mrun = 0.f, lrun = 0.f;              // mask zeros always in softmax set
    f32x4 ctx[4];
#pragma unroll
    for (int f = 0; f < 4; ++f) ctx[f] = (f32x4){0.f, 0.f, 0.f, 0.f};

    LOADT(jlo_blk);
    STORET();                                   // preload tile 0

    for (int jt = jlo_blk; jt <= jhi_blk; jt += 64) {
        const bool more = (jt + 64) <= jhi_blk;
        if (more) LOADT(jt + 64);               // T14: issue early, write late
        __syncthreads();                        // staged tile visible

        // ---- QK^T: S^T[64 keys][16 q] ----
        f32x4 sacc[4];
#pragma unroll
        for (int f = 0; f < 4; ++f) sacc[f] = (f32x4){0.f, 0.f, 0.f, 0.f};
#pragma unroll
        for (int s = 0; s < 2; ++s) {
            short8 kh[4], kl[4];
#pragma unroll
            for (int f = 0; f < 4; ++f) {
                int row = f * 16 + l15;
                int idx = (row * 64 + s * 32 + g2 * 8) ^ ((row & 7) << 3);
                kh[f] = *(const short8*)&Khi[idx];
                kl[f] = *(const short8*)&Klo[idx];
            }
#pragma unroll
            for (int f = 0; f < 4; ++f) {
                sacc[f] = __builtin_amdgcn_mfma_f32_16x16x32_bf16(kh[f], qh[s],  sacc[f], 0, 0, 0);
                sacc[f] = __builtin_amdgcn_mfma_f32_16x16x32_bf16(kh[f], qlo[s], sacc[f], 0, 0, 0);
                sacc[f] = __builtin_amdgcn_mfma_f32_16x16x32_bf16(kl[f], qh[s],  sacc[f], 0, 0, 0);
            }
        }

        // ---- softmax (lane-local rows; key j = jt + f*16 + g2*4 + r) ----
        float p[4][4];
        float tmax = -1e30f;
#pragma unroll
        for (int f = 0; f < 4; ++f)
#pragma unroll
            for (int r = 0; r < 4; ++r) {
                int j = jt + f * 16 + g2 * 4 + r;
                bool inw = (j >= i - WIN) && (j <= i + WIN);
                float sv_ = inw ? sacc[f][r] : -1e30f;
                p[f][r] = sv_;
                tmax = fmaxf(tmax, sv_);
            }
        tmax = fmaxf(tmax, __shfl_xor(tmax, 16));
        tmax = fmaxf(tmax, __shfl_xor(tmax, 32));
        float m_new = fmaxf(mrun, tmax);
        float resc  = __expf(mrun - m_new);
        float lsum  = 0.f;
#pragma unroll
        for (int f = 0; f < 4; ++f)
#pragma unroll
            for (int r = 0; r < 4; ++r) {
                float pe = __expf(p[f][r] - m_new);
                p[f][r] = pe;
                lsum += pe;
            }
        lsum += __shfl_xor(lsum, 16);
        lsum += __shfl_xor(lsum, 32);
        lrun = lrun * resc + lsum;
        mrun = m_new;
#pragma unroll
        for (int f = 0; f < 4; ++f) {
            ctx[f][0] *= resc; ctx[f][1] *= resc;
            ctx[f][2] *= resc; ctx[f][3] *= resc;
        }

        // ---- P -> bf16 hi/lo into per-wave LDS ([q][key], swizzled) ----
#pragma unroll
        for (int f = 0; f < 4; ++f) {
            ushort h0 = bf16_rne(p[f][0]), h1 = bf16_rne(p[f][1]),
                   h2 = bf16_rne(p[f][2]), h3 = bf16_rne(p[f][3]);
            ushort l0 = bf16_rne(p[f][0] - bf16_to_f(h0)),
                   l1 = bf16_rne(p[f][1] - bf16_to_f(h1)),
                   l2 = bf16_rne(p[f][2] - bf16_to_f(h2)),
                   l3 = bf16_rne(p[f][3] - bf16_to_f(h3));
            int idx = (l15 * 64 + f * 16 + g2 * 4) ^ ((l15 & 7) << 3);
            *(uint2*)&Phi_s[wv][idx] = make_uint2((uint)h0 | ((uint)h1 << 16),
                                                  (uint)h2 | ((uint)h3 << 16));
            *(uint2*)&Plo_s[wv][idx] = make_uint2((uint)l0 | ((uint)l1 << 16),
                                                  (uint)l2 | ((uint)l3 << 16));
        }

        // ---- PV: ctx^T[64 d][16 q] += V^T . P^T ----
#pragma unroll
        for (int s = 0; s < 2; ++s) {
            int pidx = (l15 * 64 + s * 32 + g2 * 8) ^ ((l15 & 7) << 3);
            short8 ph = *(const short8*)&Phi_s[wv][pidx];
            short8 pl = *(const short8*)&Plo_s[wv][pidx];
#pragma unroll
            for (int f = 0; f < 4; ++f) {
                int row = f * 16 + l15;
                int idx = (row * 64 + s * 32 + g2 * 8) ^ ((row & 7) << 3);
                short8 vh = *(const short8*)&VThi[idx];
                short8 vl = *(const short8*)&VTlo[idx];
                ctx[f] = __builtin_amdgcn_mfma_f32_16x16x32_bf16(vh, ph, ctx[f], 0, 0, 0);
                ctx[f] = __builtin_amdgcn_mfma_f32_16x16x32_bf16(vl, ph, ctx[f], 0, 0, 0);
                ctx[f] = __builtin_amdgcn_mfma_f32_16x16x32_bf16(vh, pl, ctx[f], 0, 0, 0);
            }
        }

        __syncthreads();                        // all reads of this tile done
        if (more) STORET();                     // commit prefetched tile
    }

    // ---- out-of-window correction + normalize + store ----
    const int jlo = max(0, i - WIN);
    const int jhi = min(SEQ - 1, i + WIN);
    const int cnt = jhi - jlo + 1;
    const float em   = __expf(-mrun);
    const float ltot = lrun + (float)(SEQ - cnt) * em;
    const float inv  = 1.f / ltot;

    const float* vpT = &Vpre[((size_t)bh * SEQ + (SEQ - 1)) * HDIM];
    const float* vpH = &Vpre[((size_t)bh * SEQ + jhi) * HDIM];
    const float* vpL = &Vpre[((size_t)bh * SEQ + (jlo - 1)) * HDIM];  // read only if jlo>0
    float* orow = &out[((size_t)(b * SEQ + i)) * HIDDEN + h * HDIM];

#pragma unroll
    for (int f = 0; f < 4; ++f) {
        int d0 = f * 16 + g2 * 4;
        float4 tt = *(const float4*)&vpT[d0];
        float4 hh = *(const float4*)&vpH[d0];
        float4 ll = {0.f, 0.f, 0.f, 0.f};
        if (jlo > 0) ll = *(const float4*)&vpL[d0];
        float4 o;
        o.x = (ctx[f][0] + em * (tt.x - hh.x + ll.x)) * inv;
        o.y = (ctx[f][1] + em * (tt.y - hh.y + ll.y)) * inv;
        o.z = (ctx[f][2] + em * (tt.z - hh.z + ll.z)) * inv;
        o.w = (ctx[f][3] + em * (tt.w - hh.w + ll.w)) * inv;
        *(float4*)&orow[d0] = o;
    }
}

// ---------------------------------------------------------------------------
extern "C" void kernel_launch(void* const* d_in, const int* in_sizes, int n_in,
                              void* d_out, int out_size, void* d_ws, size_t ws_size,
                              hipStream_t stream) {
    const float* X  = (const float*)d_in[0];
    const float* Wq = (const float*)d_in[1];
    const float* bq = (const float*)d_in[2];
    const float* Wk = (const float*)d_in[3];
    const float* bk = (const float*)d_in[4];
    const float* Wv = (const float*)d_in[5];
    const float* bv = (const float*)d_in[6];
    float* out = (float*)d_out;

    const size_t TEN = (size_t)BATCH * NHEAD * SEQ * HDIM;  // 3,145,728 floats
    float* qf   = (float*)d_ws;
    float* kf   = qf + TEN;
    float* vf   = kf + TEN;
    float* vpre = vf + TEN;   // 50.3 MB of ws total (R4-proven footprint)

    proj_mfma_kernel<<<dim3(MTOT / 128, NHEAD, 3), 256, 0, stream>>>(
        X, Wq, bq, Wk, bk, Wv, bv, qf, kf, vf);
    vprefix_kernel<<<dim3(BATCH * NHEAD), 256, 0, stream>>>(vf, vpre);
    attn_kernel<<<dim3((SEQ / 128) * BATCH * NHEAD), 512, 0, stream>>>(
        qf, kf, vf, vpre, out);
}

// Round 12
// 230.271 us; speedup vs baseline: 1.8718x; 1.0600x over previous
//
#include <hip/hip_runtime.h>
#include <hip/hip_bf16.h>
#include <cstdint>

// Problem constants (LongformerSelfAttention: B=2, S=2048, M=768, H=12, D=64, W=256, DIL=1)
#define SEQ    2048
#define HIDDEN 768
#define NHEAD  12
#define HDIM   64
#define WIN    256
#define BATCH  2
#define MTOT   (BATCH * SEQ)   // 4096 tokens

typedef __attribute__((ext_vector_type(8))) short short8;   // 8 bf16 = 4 VGPR (MFMA A/B frag)
typedef __attribute__((ext_vector_type(4))) float f32x4;    // MFMA C/D frag

union S8U4 { short8 s; uint4 u; };

// ---------------------------------------------------------------------------
// Pair-wise fp32 -> (hi, lo) bf16 split using v_cvt_pk_bf16_f32 (RNE).
// R10's manual bit-twiddled RNE cost ~10 VALU/float and hid the packed-cvt
// pattern from the compiler (proj VALUBusy 45%). This form is ~6 inst per
// 2 floats and bit-identical for finite inputs.
// Packing: a -> low 16 bits, b -> high 16 bits (matches previous layout).
// ---------------------------------------------------------------------------
__device__ __forceinline__ void bf16_split2(float a, float b, uint& h2, uint& l2) {
    union { __hip_bfloat162 v; uint u; } ch, cl;
    ch.v = __float22bfloat162_rn(make_float2(a, b));
    float af = __uint_as_float(ch.u << 16);           // hi(a) as f32
    float bf = __uint_as_float(ch.u & 0xFFFF0000u);   // hi(b) as f32
    cl.v = __float22bfloat162_rn(make_float2(a - af, b - bf));
    h2 = ch.u;
    l2 = cl.u;
}

// ---------------------------------------------------------------------------
// Projection GEMM via split-bf16 MFMA (R4/R10 structure, cvt_pk conversion).
// In-kernel fp32->hi/lo conversion during staging; fp32 outputs [bh][s][d]
// via 64B-segment stores (WRITE_SIZE 36.8 MB, clean).
// 1152 blocks (parallelism beats conversion amortization — R9 lesson).
// ---------------------------------------------------------------------------
__global__ __launch_bounds__(256) void proj_mfma_kernel(
    const float* __restrict__ X,
    const float* __restrict__ Wq, const float* __restrict__ bq,
    const float* __restrict__ Wk, const float* __restrict__ bk,
    const float* __restrict__ Wv, const float* __restrict__ bv,
    float* __restrict__ Qo, float* __restrict__ Ko, float* __restrict__ Vo)
{
    const int which = blockIdx.z;
    const float* __restrict__ W    = (which == 0) ? Wq : (which == 1) ? Wk : Wv;
    const float* __restrict__ bias = (which == 0) ? bq : (which == 1) ? bk : bv;
    float* __restrict__ out        = (which == 0) ? Qo : (which == 1) ? Ko : Vo;
    const float scale = (which == 0) ? 0.125f : 1.0f;

    __shared__ __align__(16) ushort Ahi[128 * 64];
    __shared__ __align__(16) ushort Alo[128 * 64];
    __shared__ __align__(16) ushort Bhi[64 * 64];
    __shared__ __align__(16) ushort Blo[64 * 64];

    const int t  = threadIdx.x;
    const int m0 = blockIdx.x * 128;
    const int h  = blockIdx.y;
    const int n0 = h * 64;

    const int w    = t >> 6;
    const int lane = t & 63;
    const int wr   = w >> 1;
    const int wc   = w & 1;
    const int lr   = lane & 15;
    const int lk   = lane >> 4;

    f32x4 acc[4][2];
#pragma unroll
    for (int i = 0; i < 4; ++i)
#pragma unroll
        for (int j = 0; j < 2; ++j) acc[i][j] = (f32x4){0.f, 0.f, 0.f, 0.f};

    for (int k0 = 0; k0 < HIDDEN; k0 += 64) {
        __syncthreads();
#pragma unroll
        for (int i = 0; i < 8; ++i) {
            int id  = t + i * 256;
            int row = id >> 4;
            int c4  = id & 15;
            const float4 xv = *(const float4*)&X[(size_t)(m0 + row) * HIDDEN + k0 + c4 * 4];
            uint h01, l01, h23, l23;
            bf16_split2(xv.x, xv.y, h01, l01);
            bf16_split2(xv.z, xv.w, h23, l23);
            int idx = (row * 64 + c4 * 4) ^ ((row & 7) << 3);
            *(uint2*)&Ahi[idx] = make_uint2(h01, h23);
            *(uint2*)&Alo[idx] = make_uint2(l01, l23);
        }
#pragma unroll
        for (int i = 0; i < 4; ++i) {
            int id  = t + i * 256;
            int row = id >> 4;
            int c4  = id & 15;
            const float4 wv4 = *(const float4*)&W[(size_t)(n0 + row) * HIDDEN + k0 + c4 * 4];
            uint h01, l01, h23, l23;
            bf16_split2(wv4.x, wv4.y, h01, l01);
            bf16_split2(wv4.z, wv4.w, h23, l23);
            int idx = (row * 64 + c4 * 4) ^ ((row & 7) << 3);
            *(uint2*)&Bhi[idx] = make_uint2(h01, h23);
            *(uint2*)&Blo[idx] = make_uint2(l01, l23);
        }
        __syncthreads();

#pragma unroll
        for (int s = 0; s < 2; ++s) {
            short8 ah[4], al[4], bh2[2], bl2[2];
#pragma unroll
            for (int fm = 0; fm < 4; ++fm) {
                int row = wr * 64 + fm * 16 + lr;
                int idx = (row * 64 + s * 32 + lk * 8) ^ ((row & 7) << 3);
                ah[fm] = *(const short8*)&Ahi[idx];
                al[fm] = *(const short8*)&Alo[idx];
            }
#pragma unroll
            for (int fn = 0; fn < 2; ++fn) {
                int row = wc * 32 + fn * 16 + lr;
                int idx = (row * 64 + s * 32 + lk * 8) ^ ((row & 7) << 3);
                bh2[fn] = *(const short8*)&Bhi[idx];
                bl2[fn] = *(const short8*)&Blo[idx];
            }
#pragma unroll
            for (int fm = 0; fm < 4; ++fm)
#pragma unroll
                for (int fn = 0; fn < 2; ++fn) {
                    acc[fm][fn] = __builtin_amdgcn_mfma_f32_16x16x32_bf16(
                        ah[fm], bh2[fn], acc[fm][fn], 0, 0, 0);
                    acc[fm][fn] = __builtin_amdgcn_mfma_f32_16x16x32_bf16(
                        ah[fm], bl2[fn], acc[fm][fn], 0, 0, 0);
                    acc[fm][fn] = __builtin_amdgcn_mfma_f32_16x16x32_bf16(
                        al[fm], bh2[fn], acc[fm][fn], 0, 0, 0);
                }
        }
    }

    // ---- epilogue: fp32 stores, 64B contiguous per 16-lane group ----
#pragma unroll
    for (int fn = 0; fn < 2; ++fn) {
        int d = wc * 32 + fn * 16 + lr;
        float bval = bias[n0 + d];
#pragma unroll
        for (int fm = 0; fm < 4; ++fm) {
#pragma unroll
            for (int r = 0; r < 4; ++r) {
                int m  = m0 + wr * 64 + fm * 16 + lk * 4 + r;
                int bb = m >> 11;
                int ss = m & (SEQ - 1);
                out[(((size_t)(bb * NHEAD + h) * SEQ) + ss) * HDIM + d] =
                    (acc[fm][fn][r] + bval) * scale;
            }
        }
    }
}

// ---------------------------------------------------------------------------
// Prefix sum of V along sequence per (b,h,d) (unchanged).
// ---------------------------------------------------------------------------
__global__ __launch_bounds__(256) void vprefix_kernel(
    const float* __restrict__ V, float* __restrict__ Vpre)
{
    const int bh    = blockIdx.x;
    const int d     = threadIdx.x & 63;
    const int chunk = threadIdx.x >> 6;
    const float* vb = &V[(size_t)bh * SEQ * HDIM];
    float* pb       = &Vpre[(size_t)bh * SEQ * HDIM];

    __shared__ float csum[4][64];
    const int s0 = chunk * 512;
    float sum = 0.f;
    for (int s = s0; s < s0 + 512; ++s) sum += vb[(size_t)s * HDIM + d];
    csum[chunk][d] = sum;
    __syncthreads();
    float run = 0.f;
    for (int c = 0; c < chunk; ++c) run += csum[c][d];
    for (int s = s0; s < s0 + 512; ++s) {
        run += vb[(size_t)s * HDIM + d];
        pb[(size_t)s * HDIM + d] = run;
    }
}

// ---------------------------------------------------------------------------
// Banded attention (R10 structure — QBLK=128, 512 threads, 8 waves; split-bf16
// MFMA, swapped operands, lane-local softmax, Vpre mask correction) with
// cvt_pk-based conversions at every site (K/V staging, P, Q frags).
// ---------------------------------------------------------------------------
__global__ __launch_bounds__(512, 2) void attn_kernel(
    const float* __restrict__ Q, const float* __restrict__ K,
    const float* __restrict__ V, const float* __restrict__ Vpre,
    float* __restrict__ out)
{
    __shared__ __align__(16) ushort Khi[64 * 64], Klo[64 * 64];   // [key][d] ^((key&7)<<3)
    __shared__ __align__(16) ushort VThi[64 * 64], VTlo[64 * 64]; // [d][key] ^((d&7)<<3)
    __shared__ __align__(16) ushort Phi_s[8][16 * 64];            // per-wave [q][key] ^((q&7)<<3)
    __shared__ __align__(16) ushort Plo_s[8][16 * 64];

    const int t    = threadIdx.x;
    const int lane = t & 63;
    const int wv   = t >> 6;                   // wave 0..7 -> q rows wv*16..+15
    const int l15  = lane & 15;
    const int g2   = lane >> 4;                // 0..3

    const int L    = blockIdx.x;               // 384 blocks
    const int xcd  = L & 7;
    const int slot = L >> 3;                   // 0..47
    const int bh   = xcd * 3 + (slot >> 4);    // 0..23
    const int qb   = slot & 15;                // 0..15
    const int b    = bh / NHEAD;
    const int h    = bh % NHEAD;
    const int i0   = qb * 128;
    const int i    = i0 + wv * 16 + l15;       // this lane's q row (acc column)

    const float* kbase = &K[(size_t)bh * SEQ * HDIM];
    const float* vbase = &V[(size_t)bh * SEQ * HDIM];

    // ---- Q fragments (B-operand), hoisted, hi/lo via cvt_pk ----
    short8 qh[2], qlo[2];
    {
        const float* qrow = &Q[((size_t)bh * SEQ + i) * HDIM];
#pragma unroll
        for (int s = 0; s < 2; ++s) {
            float4 a = *(const float4*)&qrow[s * 32 + g2 * 8];
            float4 c = *(const float4*)&qrow[s * 32 + g2 * 8 + 4];
            S8U4 H, L;
            bf16_split2(a.x, a.y, H.u.x, L.u.x);
            bf16_split2(a.z, a.w, H.u.y, L.u.y);
            bf16_split2(c.x, c.y, H.u.z, L.u.z);
            bf16_split2(c.z, c.w, H.u.w, L.u.w);
            qh[s]  = H.s;
            qlo[s] = L.s;
        }
    }

    // ---- staging assignment (512 threads; 8 K-floats + 8 V-floats each) ----
    const int krow = t >> 3;                   // 0..63 (key row)
    const int kc   = (t & 7) * 8;              // d offset, 8 floats
    const int vkp  = t >> 4;                   // 0..31 -> keys 2vkp, 2vkp+1
    const int vdc  = (t & 15) * 4;             // d offset, 4 floats
    float4 kpre[2], vp0, vp1;

    const int jlo_blk = max(0, i0 - WIN);
    const int jhi_blk = min(SEQ - 1, i0 + 127 + WIN);

    auto LOADT = [&](int jt2) {
        const float* kr = &kbase[(size_t)(jt2 + krow) * HDIM + kc];
        kpre[0] = *(const float4*)&kr[0];
        kpre[1] = *(const float4*)&kr[4];
        vp0 = *(const float4*)&vbase[(size_t)(jt2 + 2 * vkp) * HDIM + vdc];
        vp1 = *(const float4*)&vbase[(size_t)(jt2 + 2 * vkp + 1) * HDIM + vdc];
    };
    auto STORET = [&]() {
#pragma unroll
        for (int c = 0; c < 2; ++c) {
            uint h01, l01, h23, l23;
            bf16_split2(kpre[c].x, kpre[c].y, h01, l01);
            bf16_split2(kpre[c].z, kpre[c].w, h23, l23);
            int idx = (krow * 64 + kc + c * 4) ^ ((krow & 7) << 3);
            *(uint2*)&Khi[idx] = make_uint2(h01, h23);
            *(uint2*)&Klo[idx] = make_uint2(l01, l23);
        }
        float va[4] = {vp0.x, vp0.y, vp0.z, vp0.w};
        float vb4[4] = {vp1.x, vp1.y, vp1.z, vp1.w};
#pragma unroll
        for (int j = 0; j < 4; ++j) {
            int d = vdc + j;
            uint hj, lj;
            bf16_split2(va[j], vb4[j], hj, lj);   // key 2vkp low, 2vkp+1 high
            int idx = (d * 64 + 2 * vkp) ^ ((d & 7) << 3);
            *(uint*)&VThi[idx] = hj;
            *(uint*)&VTlo[idx] = lj;
        }
    };

    float mrun = 0.f, lrun = 0.f;              // mask zeros always in softmax set
    f32x4 ctx[4];
#pragma unroll
    for (int f = 0; f < 4; ++f) ctx[f] = (f32x4){0.f, 0.f, 0.f, 0.f};

    LOADT(jlo_blk);
    STORET();                                   // preload tile 0

    for (int jt = jlo_blk; jt <= jhi_blk; jt += 64) {
        const bool more = (jt + 64) <= jhi_blk;
        if (more) LOADT(jt + 64);               // T14: issue early, write late
        __syncthreads();                        // staged tile visible

        // ---- QK^T: S^T[64 keys][16 q] ----
        f32x4 sacc[4];
#pragma unroll
        for (int f = 0; f < 4; ++f) sacc[f] = (f32x4){0.f, 0.f, 0.f, 0.f};
#pragma unroll
        for (int s = 0; s < 2; ++s) {
            short8 kh[4], kl[4];
#pragma unroll
            for (int f = 0; f < 4; ++f) {
                int row = f * 16 + l15;
                int idx = (row * 64 + s * 32 + g2 * 8) ^ ((row & 7) << 3);
                kh[f] = *(const short8*)&Khi[idx];
                kl[f] = *(const short8*)&Klo[idx];
            }
#pragma unroll
            for (int f = 0; f < 4; ++f) {
                sacc[f] = __builtin_amdgcn_mfma_f32_16x16x32_bf16(kh[f], qh[s],  sacc[f], 0, 0, 0);
                sacc[f] = __builtin_amdgcn_mfma_f32_16x16x32_bf16(kh[f], qlo[s], sacc[f], 0, 0, 0);
                sacc[f] = __builtin_amdgcn_mfma_f32_16x16x32_bf16(kl[f], qh[s],  sacc[f], 0, 0, 0);
            }
        }

        // ---- softmax (lane-local rows; key j = jt + f*16 + g2*4 + r) ----
        float p[4][4];
        float tmax = -1e30f;
#pragma unroll
        for (int f = 0; f < 4; ++f)
#pragma unroll
            for (int r = 0; r < 4; ++r) {
                int j = jt + f * 16 + g2 * 4 + r;
                bool inw = (j >= i - WIN) && (j <= i + WIN);
                float sv_ = inw ? sacc[f][r] : -1e30f;
                p[f][r] = sv_;
                tmax = fmaxf(tmax, sv_);
            }
        tmax = fmaxf(tmax, __shfl_xor(tmax, 16));
        tmax = fmaxf(tmax, __shfl_xor(tmax, 32));
        float m_new = fmaxf(mrun, tmax);
        float resc  = __expf(mrun - m_new);
        float lsum  = 0.f;
#pragma unroll
        for (int f = 0; f < 4; ++f)
#pragma unroll
            for (int r = 0; r < 4; ++r) {
                float pe = __expf(p[f][r] - m_new);
                p[f][r] = pe;
                lsum += pe;
            }
        lsum += __shfl_xor(lsum, 16);
        lsum += __shfl_xor(lsum, 32);
        lrun = lrun * resc + lsum;
        mrun = m_new;
#pragma unroll
        for (int f = 0; f < 4; ++f) {
            ctx[f][0] *= resc; ctx[f][1] *= resc;
            ctx[f][2] *= resc; ctx[f][3] *= resc;
        }

        // ---- P -> bf16 hi/lo into per-wave LDS ([q][key], swizzled) ----
#pragma unroll
        for (int f = 0; f < 4; ++f) {
            uint h01, l01, h23, l23;
            bf16_split2(p[f][0], p[f][1], h01, l01);
            bf16_split2(p[f][2], p[f][3], h23, l23);
            int idx = (l15 * 64 + f * 16 + g2 * 4) ^ ((l15 & 7) << 3);
            *(uint2*)&Phi_s[wv][idx] = make_uint2(h01, h23);
            *(uint2*)&Plo_s[wv][idx] = make_uint2(l01, l23);
        }

        // ---- PV: ctx^T[64 d][16 q] += V^T . P^T ----
#pragma unroll
        for (int s = 0; s < 2; ++s) {
            int pidx = (l15 * 64 + s * 32 + g2 * 8) ^ ((l15 & 7) << 3);
            short8 ph = *(const short8*)&Phi_s[wv][pidx];
            short8 pl = *(const short8*)&Plo_s[wv][pidx];
#pragma unroll
            for (int f = 0; f < 4; ++f) {
                int row = f * 16 + l15;
                int idx = (row * 64 + s * 32 + g2 * 8) ^ ((row & 7) << 3);
                short8 vh = *(const short8*)&VThi[idx];
                short8 vl = *(const short8*)&VTlo[idx];
                ctx[f] = __builtin_amdgcn_mfma_f32_16x16x32_bf16(vh, ph, ctx[f], 0, 0, 0);
                ctx[f] = __builtin_amdgcn_mfma_f32_16x16x32_bf16(vl, ph, ctx[f], 0, 0, 0);
                ctx[f] = __builtin_amdgcn_mfma_f32_16x16x32_bf16(vh, pl, ctx[f], 0, 0, 0);
            }
        }

        __syncthreads();                        // all reads of this tile done
        if (more) STORET();                     // commit prefetched tile
    }

    // ---- out-of-window correction + normalize + store ----
    const int jlo = max(0, i - WIN);
    const int jhi = min(SEQ - 1, i + WIN);
    const int cnt = jhi - jlo + 1;
    const float em   = __expf(-mrun);
    const float ltot = lrun + (float)(SEQ - cnt) * em;
    const float inv  = 1.f / ltot;

    const float* vpT = &Vpre[((size_t)bh * SEQ + (SEQ - 1)) * HDIM];
    const float* vpH = &Vpre[((size_t)bh * SEQ + jhi) * HDIM];
    const float* vpL = &Vpre[((size_t)bh * SEQ + (jlo - 1)) * HDIM];  // read only if jlo>0
    float* orow = &out[((size_t)(b * SEQ + i)) * HIDDEN + h * HDIM];

#pragma unroll
    for (int f = 0; f < 4; ++f) {
        int d0 = f * 16 + g2 * 4;
        float4 tt = *(const float4*)&vpT[d0];
        float4 hh = *(const float4*)&vpH[d0];
        float4 ll = {0.f, 0.f, 0.f, 0.f};
        if (jlo > 0) ll = *(const float4*)&vpL[d0];
        float4 o;
        o.x = (ctx[f][0] + em * (tt.x - hh.x + ll.x)) * inv;
        o.y = (ctx[f][1] + em * (tt.y - hh.y + ll.y)) * inv;
        o.z = (ctx[f][2] + em * (tt.z - hh.z + ll.z)) * inv;
        o.w = (ctx[f][3] + em * (tt.w - hh.w + ll.w)) * inv;
        *(float4*)&orow[d0] = o;
    }
}

// ---------------------------------------------------------------------------
extern "C" void kernel_launch(void* const* d_in, const int* in_sizes, int n_in,
                              void* d_out, int out_size, void* d_ws, size_t ws_size,
                              hipStream_t stream) {
    const float* X  = (const float*)d_in[0];
    const float* Wq = (const float*)d_in[1];
    const float* bq = (const float*)d_in[2];
    const float* Wk = (const float*)d_in[3];
    const float* bk = (const float*)d_in[4];
    const float* Wv = (const float*)d_in[5];
    const float* bv = (const float*)d_in[6];
    float* out = (float*)d_out;

    const size_t TEN = (size_t)BATCH * NHEAD * SEQ * HDIM;  // 3,145,728 floats
    float* qf   = (float*)d_ws;
    float* kf   = qf + TEN;
    float* vf   = kf + TEN;
    float* vpre = vf + TEN;   // 50.3 MB of ws total

    proj_mfma_kernel<<<dim3(MTOT / 128, NHEAD, 3), 256, 0, stream>>>(
        X, Wq, bq, Wk, bk, Wv, bv, qf, kf, vf);
    vprefix_kernel<<<dim3(BATCH * NHEAD), 256, 0, stream>>>(vf, vpre);
    attn_kernel<<<dim3((SEQ / 128) * BATCH * NHEAD), 512, 0, stream>>>(
        qf, kf, vf, vpre, out);
}